// Round 11
// baseline (1241.177 us; speedup 1.0000x reference)
//
#include <hip/hip_runtime.h>
#include <cstdint>
#include <cstddef>

#define L_SEQ 2048
#define DMODEL 1024
#define NHEAD 16
#define DHEAD 64
#define FFN_F 4096
#define VOCAB 32000
#define NLAYER 4

typedef __attribute__((ext_vector_type(8))) short short8;
typedef __attribute__((ext_vector_type(4))) float f32x4;

__device__ __forceinline__ unsigned short f2bf(float f) {
  unsigned int u = __float_as_uint(f);
  u += 0x7fffu + ((u >> 16) & 1u);
  return (unsigned short)(u >> 16);
}
__device__ __forceinline__ float b2f(unsigned short h) {
  return __uint_as_float(((unsigned int)h) << 16);
}

__device__ __forceinline__ void glds16(const unsigned short* g, unsigned short* l) {
  __builtin_amdgcn_global_load_lds(
      (const __attribute__((address_space(1))) unsigned int*)g,
      (__attribute__((address_space(3))) unsigned int*)l, 16, 0, 0);
}

__device__ __forceinline__ float rmax16(float v) {
  v = fmaxf(v, __shfl_xor(v, 1));
  v = fmaxf(v, __shfl_xor(v, 2));
  v = fmaxf(v, __shfl_xor(v, 4));
  v = fmaxf(v, __shfl_xor(v, 8));
  return v;
}
__device__ __forceinline__ float rsum16(float v) {
  v += __shfl_xor(v, 1);
  v += __shfl_xor(v, 2);
  v += __shfl_xor(v, 4);
  v += __shfl_xor(v, 8);
  return v;
}

#define MFMA(ACC, AF, BF) \
  ACC = __builtin_amdgcn_mfma_f32_16x16x32_bf16(AF, BF, ACC, 0, 0, 0)

enum { E_F32 = 0, E_BF16 = 1, E_SWIGLU = 2, E_PART = 3, E_QKVT = 4 };

// ============ 8-phase 256x256 GEMM (T2+T3+T4+T5), 512 thr, BK=64 ============
template <int EPI>
__global__ __launch_bounds__(512, 2) void gemm8p(
    const unsigned short* __restrict__ A, const unsigned short* __restrict__ B,
    void* __restrict__ Cg, int M, int N, int K, int lda, int ldb, int ldc,
    float alpha, int nby)
{
  const int nwg = gridDim.x;
  const int orig = blockIdx.x;
  const int q = nwg >> 3, r = nwg & 7;
  const int xcd = orig & 7, rest = orig >> 3;
  const int wgid = (xcd < r ? xcd * (q + 1) : r * (q + 1) + (xcd - r) * q) + rest;
  const int by = wgid % nby, bx = wgid / nby;
  const int mb = by * 256, nb = bx * 256;

  __shared__ __align__(16) unsigned short As_[2][256 * 64];
  __shared__ __align__(16) unsigned short Bs_[2][256 * 64];

  const int tid = threadIdx.x;
  const int lane = tid & 63;
  const int w = tid >> 6;
  const int wm = (w >> 2) * 128;
  const int wn = (w & 3) * 64;
  const int lr = lane & 15;
  const int lg = lane >> 4;
  const int srow = lane >> 3;
  const int scol = ((lane & 7) ^ srow) * 8;
  const int slot0 = (lg ^ (lr & 7)) * 8;
  const int slot1 = ((4 + lg) ^ (lr & 7)) * 8;

  f32x4 acc[8][4];
#pragma unroll
  for (int i = 0; i < 8; i++)
#pragma unroll
    for (int j = 0; j < 4; j++) acc[i][j] = (f32x4){0.f, 0.f, 0.f, 0.f};

  const unsigned short* Ab = A + (size_t)(mb + srow) * lda + scol;
  const unsigned short* Bb = B + (size_t)(nb + srow) * ldb + scol;

  auto stageA = [&](int t, int R) {
    const int s = t & 1, kb = t << 6;
#pragma unroll
    for (int c = 0; c < 2; c++) {
      int cid = w * 2 + c;
      int rb = ((cid >> 3) << 7) + R * 64 + ((cid & 7) << 3);
      glds16(Ab + (size_t)rb * lda + kb, &As_[s][rb * 64]);
    }
  };
  auto stageB = [&](int t, int R) {
    const int s = t & 1, kb = t << 6;
#pragma unroll
    for (int c = 0; c < 2; c++) {
      int cid = w * 2 + c;
      int rb = ((cid >> 2) << 6) + R * 32 + ((cid & 3) << 3);
      glds16(Bb + (size_t)rb * ldb + kb, &Bs_[s][rb * 64]);
    }
  };

  const int nk = K >> 6;
  stageA(0, 0); stageA(0, 1); stageB(0, 0); stageB(0, 1);
  stageA(1, 0); stageB(1, 0); stageB(1, 1);
  asm volatile("s_waitcnt vmcnt(6)" ::: "memory");
  __builtin_amdgcn_s_barrier();

  short8 a[4][2], b0[2][2], b1[2][2];
#pragma unroll
  for (int j = 0; j < 2; j++) {
    b0[j][0] = *(const short8*)&Bs_[0][(wn + j * 16 + lr) * 64 + slot0];
    b0[j][1] = *(const short8*)&Bs_[0][(wn + j * 16 + lr) * 64 + slot1];
  }

  for (int t = 0; t < nk; ++t) {
    const int s = t & 1;
    const unsigned short* Asb = &As_[s][0];
    const unsigned short* Bsb = &Bs_[s][0];

    // phase 1: read A-low; stage A-R2(t+1); MFMA (m-lo x n-lo)
#pragma unroll
    for (int i = 0; i < 4; i++) {
      a[i][0] = *(const short8*)&Asb[(wm + i * 16 + lr) * 64 + slot0];
      a[i][1] = *(const short8*)&Asb[(wm + i * 16 + lr) * 64 + slot1];
    }
    if (t + 1 < nk) stageA(t + 1, 1);
    __builtin_amdgcn_s_barrier();
    __builtin_amdgcn_s_setprio(1);
#pragma unroll
    for (int kk = 0; kk < 2; kk++)
#pragma unroll
      for (int i = 0; i < 4; i++)
#pragma unroll
        for (int j = 0; j < 2; j++) MFMA(acc[i][j], a[i][kk], b0[j][kk]);
    __builtin_amdgcn_s_setprio(0);
    __builtin_amdgcn_s_barrier();

    // phase 2: read B-high; stage A-R1(t+2); MFMA (m-lo x n-hi)
#pragma unroll
    for (int j = 0; j < 2; j++) {
      b1[j][0] = *(const short8*)&Bsb[(wn + 32 + j * 16 + lr) * 64 + slot0];
      b1[j][1] = *(const short8*)&Bsb[(wn + 32 + j * 16 + lr) * 64 + slot1];
    }
    if (t + 2 < nk) stageA(t + 2, 0);
    __builtin_amdgcn_s_barrier();
    __builtin_amdgcn_s_setprio(1);
#pragma unroll
    for (int kk = 0; kk < 2; kk++)
#pragma unroll
      for (int i = 0; i < 4; i++)
#pragma unroll
        for (int j = 0; j < 2; j++) MFMA(acc[i][2 + j], a[i][kk], b1[j][kk]);
    __builtin_amdgcn_s_setprio(0);
    __builtin_amdgcn_s_barrier();

    // phase 3: read A-high; stage B-R1(t+2); MFMA (m-hi x n-hi)
#pragma unroll
    for (int i = 0; i < 4; i++) {
      a[i][0] = *(const short8*)&Asb[(wm + 64 + i * 16 + lr) * 64 + slot0];
      a[i][1] = *(const short8*)&Asb[(wm + 64 + i * 16 + lr) * 64 + slot1];
    }
    if (t + 2 < nk) stageB(t + 2, 0);
    __builtin_amdgcn_s_barrier();
    __builtin_amdgcn_s_setprio(1);
#pragma unroll
    for (int kk = 0; kk < 2; kk++)
#pragma unroll
      for (int i = 0; i < 4; i++)
#pragma unroll
        for (int j = 0; j < 2; j++) MFMA(acc[4 + i][2 + j], a[i][kk], b1[j][kk]);
    __builtin_amdgcn_s_setprio(0);
    __builtin_amdgcn_s_barrier();

    // phase 4: stage B-R2(t+2); MFMA (m-hi x n-lo); counted vmcnt; tail b0 read
    if (t + 2 < nk) stageB(t + 2, 1);
    __builtin_amdgcn_s_barrier();
    __builtin_amdgcn_s_setprio(1);
#pragma unroll
    for (int kk = 0; kk < 2; kk++)
#pragma unroll
      for (int i = 0; i < 4; i++)
#pragma unroll
        for (int j = 0; j < 2; j++) MFMA(acc[4 + i][j], a[i][kk], b0[j][kk]);
    __builtin_amdgcn_s_setprio(0);
    if (t + 2 < nk) {
      asm volatile("s_waitcnt vmcnt(6)" ::: "memory");
    } else {
      asm volatile("s_waitcnt vmcnt(0)" ::: "memory");
    }
    __builtin_amdgcn_s_barrier();
    if (t + 1 < nk) {
      const unsigned short* Bn = &Bs_[s ^ 1][0];
#pragma unroll
      for (int j = 0; j < 2; j++) {
        b0[j][0] = *(const short8*)&Bn[(wn + j * 16 + lr) * 64 + slot0];
        b0[j][1] = *(const short8*)&Bn[(wn + j * 16 + lr) * 64 + slot1];
      }
    }
  }

#pragma unroll
  for (int i = 0; i < 8; i++) {
#pragma unroll
    for (int j = 0; j < 4; j++) {
      int oc = nb + wn + 16 * j + lr;
#pragma unroll
      for (int r4 = 0; r4 < 4; r4++) {
        int orow = mb + wm + 16 * i + lg * 4 + r4;
        float v = acc[i][j][r4] * alpha;
        if (EPI == E_F32) {
          ((float*)Cg)[(size_t)orow * ldc + oc] = v;
        } else if (EPI == E_BF16) {
          ((unsigned short*)Cg)[(size_t)orow * ldc + oc] = f2bf(v);
        } else if (EPI == E_SWIGLU) {
          float other = __shfl_xor(v, 1);
          float g = (lane & 1) ? other : v;
          float vv = (lane & 1) ? v : other;
          float sw = g / (1.0f + expf(-g)) * vv;
          if (!(lane & 1))
            ((unsigned short*)Cg)[(size_t)orow * ldc + (oc >> 1)] = f2bf(sw);
        }
      }
    }
  }
}

// ============ 128x128 2-phase GEMM ==========================================
template <int EPI>
__global__ __launch_bounds__(256) void gemm_fast(
    const unsigned short* __restrict__ A, const unsigned short* __restrict__ B,
    void* __restrict__ Cg, void* __restrict__ Cg2,
    int M, int N, int K, int lda, int ldb, int ldc,
    float alpha, int nbx)
{
  const int nwg = gridDim.x;
  const int orig = blockIdx.x;
  const int q = nwg >> 3, r = nwg & 7;
  const int xcd = orig & 7, rest = orig >> 3;
  const int wgid = (xcd < r ? xcd * (q + 1) : r * (q + 1) + (xcd - r) * q) + rest;
  const int bx = wgid % nbx, by = wgid / nbx;
  const int mb = by * 128;
  const int nb = bx * 128;

  const int Keff = (EPI == E_PART) ? (K >> 1) : K;
  const int koff = (EPI == E_PART) ? blockIdx.z * Keff : 0;

  __shared__ __align__(16) unsigned short As[2][128 * 64];
  __shared__ __align__(16) unsigned short Bs[2][128 * 64];

  const int tid = threadIdx.x;
  const int lane = tid & 63;
  const int wave = tid >> 6;
  const int wm = (wave >> 1) * 64;
  const int wn = (wave & 1) * 64;
  const int lr = lane & 15;
  const int lg = lane >> 4;

  const int srow = lane >> 3;
  const int scol = ((lane & 7) ^ srow) * 8;

  f32x4 acc[4][4];
#pragma unroll
  for (int i = 0; i < 4; i++)
#pragma unroll
    for (int j = 0; j < 4; j++) acc[i][j] = (f32x4){0.f, 0.f, 0.f, 0.f};

  const unsigned short* Abase = A + (size_t)(mb + wave * 32 + srow) * lda + koff + scol;
  const unsigned short* Bbase = B + (size_t)(nb + wave * 32 + srow) * ldb + koff + scol;

  auto stage = [&](int kb, int b) {
#pragma unroll
    for (int c = 0; c < 4; c++)
      glds16(Abase + (size_t)(c * 8) * lda + kb, &As[b][(wave * 32 + c * 8) * 64]);
#pragma unroll
    for (int c = 0; c < 4; c++)
      glds16(Bbase + (size_t)(c * 8) * ldb + kb, &Bs[b][(wave * 32 + c * 8) * 64]);
  };

  stage(0, 0);
  __syncthreads();
  int cur = 0;
  const int nk = Keff >> 6;

  for (int t = 0; t < nk; ++t) {
    if (t + 1 < nk) stage((t + 1) << 6, cur ^ 1);

    short8 af[2][4], bfb[2][4];
#pragma unroll
    for (int h = 0; h < 2; h++) {
      const int swz = ((h * 4 + lg) ^ (lr & 7)) * 8;
#pragma unroll
      for (int i = 0; i < 4; i++) {
        af[h][i] = *(const short8*)&As[cur][(wm + 16 * i + lr) * 64 + swz];
        bfb[h][i] = *(const short8*)&Bs[cur][(wn + 16 * i + lr) * 64 + swz];
      }
    }
#pragma unroll
    for (int h = 0; h < 2; h++)
#pragma unroll
      for (int i = 0; i < 4; i++)
#pragma unroll
        for (int j = 0; j < 4; j++) MFMA(acc[i][j], af[h][i], bfb[h][j]);

    __syncthreads();
    cur ^= 1;
  }

#pragma unroll
  for (int i = 0; i < 4; i++) {
#pragma unroll
    for (int j = 0; j < 4; j++) {
      int oc = nb + wn + 16 * j + lr;
#pragma unroll
      for (int r4 = 0; r4 < 4; r4++) {
        int orow = mb + wm + 16 * i + lg * 4 + r4;
        float v = acc[i][j][r4] * alpha;
        if (EPI == E_F32) {
          ((float*)Cg)[(size_t)orow * ldc + oc] = v;
        } else if (EPI == E_BF16) {
          ((unsigned short*)Cg)[(size_t)orow * ldc + oc] = f2bf(v);
        } else if (EPI == E_QKVT) {
          // cols [0,2048): Q|K rows of qkvb (ld 2048); cols [2048,3072): V^T
          if (oc < 2048)
            ((unsigned short*)Cg)[(size_t)orow * 2048 + oc] = f2bf(v);
          else
            ((unsigned short*)Cg2)[(size_t)(oc - 2048) * L_SEQ + orow] = f2bf(v);
        } else {  // E_PART
          float* C = (float*)Cg + (size_t)blockIdx.z * ((size_t)L_SEQ * DMODEL);
          C[(size_t)orow * ldc + oc] = v;
        }
      }
    }
  }
}

// ---------------- fused flash attention (balanced, QBLK=64, 2 waves) --------
__global__ __launch_bounds__(128) void flash_attn(
    const unsigned short* __restrict__ Qg, const unsigned short* __restrict__ Kg,
    const unsigned short* __restrict__ Vt, unsigned short* __restrict__ Og,
    int ldq, int ldo)
{
  const int bid = blockIdx.x;
  const int slot = bid & 255, ph = bid >> 8;
  const int h = slot >> 4;
  const int qs = slot & 15;
  const int qb = ph ? (31 - qs) : qs;

  const int tid = threadIdx.x;
  const int lane = tid & 63;
  const int w = tid >> 6;
  const int lr = lane & 15;
  const int lg = lane >> 4;

  __shared__ __align__(16) unsigned short KsL[2][64 * 64];
  __shared__ __align__(16) unsigned short VsL[2][64 * 64];
  __shared__ __align__(16) unsigned short Ps[2][32 * 64];

  const int srow = lane >> 3;
  const int scol = ((lane & 7) ^ srow) * 8;

  short8 qf[2][2];
#pragma unroll
  for (int i = 0; i < 2; i++)
#pragma unroll
    for (int kk = 0; kk < 2; kk++)
      qf[i][kk] = *(const short8*)(Qg +
          (size_t)(qb * 64 + w * 32 + i * 16 + lr) * ldq + h * 64 + kk * 32 + lg * 8);

  f32x4 acc_o[2][4];
  float m_st[2][4], l_st[2][4];
#pragma unroll
  for (int i = 0; i < 2; i++)
#pragma unroll
    for (int j = 0; j < 4; j++) acc_o[i][j] = (f32x4){0.f, 0.f, 0.f, 0.f};
#pragma unroll
  for (int i = 0; i < 2; i++)
#pragma unroll
    for (int r = 0; r < 4; r++) { m_st[i][r] = -1e30f; l_st[i][r] = 0.f; }

  const int ntiles = qb + 1;
  const int qmin = qb * 64 + w * 32;

  auto stage = [&](int t, int buf) {
#pragma unroll
    for (int c = 0; c < 4; c++) {
      int row = w * 32 + c * 8 + srow;
      glds16(Kg + (size_t)(t * 64 + row) * ldq + h * 64 + scol,
             &KsL[buf][row * 64]);
      glds16(Vt + (size_t)(h * 64 + row) * L_SEQ + t * 64 + scol,
             &VsL[buf][row * 64]);
    }
  };

  stage(0, 0);
  __syncthreads();
  int buf = 0;

  for (int t = 0; t < ntiles; t++) {
    if (t + 1 < ntiles) stage(t + 1, buf ^ 1);

    f32x4 sa[2][4];
#pragma unroll
    for (int i = 0; i < 2; i++)
#pragma unroll
      for (int j = 0; j < 4; j++) sa[i][j] = (f32x4){0.f, 0.f, 0.f, 0.f};
#pragma unroll
    for (int kk = 0; kk < 2; kk++) {
      short8 kf[4];
#pragma unroll
      for (int j = 0; j < 4; j++)
        kf[j] = *(const short8*)&KsL[buf][(j * 16 + lr) * 64 + ((kk * 4 + lg) ^ (lr & 7)) * 8];
#pragma unroll
      for (int i = 0; i < 2; i++)
#pragma unroll
        for (int j = 0; j < 4; j++) MFMA(sa[i][j], qf[i][kk], kf[j]);
    }

    const bool diag = (t * 64 + 63) > qmin;
#pragma unroll
    for (int i = 0; i < 2; i++)
#pragma unroll
      for (int j = 0; j < 4; j++)
#pragma unroll
        for (int r = 0; r < 4; r++) {
          float s = sa[i][j][r] * 0.125f;
          if (diag) {
            int kg = t * 64 + j * 16 + lr;
            int qg = qmin + i * 16 + lg * 4 + r;
            if (kg > qg) s = -1e30f;
          }
          sa[i][j][r] = s;
        }

    float fsc[2][4], mnew[2][4];
#pragma unroll
    for (int i = 0; i < 2; i++)
#pragma unroll
      for (int r = 0; r < 4; r++) {
        float mx = fmaxf(fmaxf(sa[i][0][r], sa[i][1][r]), fmaxf(sa[i][2][r], sa[i][3][r]));
        mx = rmax16(mx);
        float mn = fmaxf(m_st[i][r], mx);
        mnew[i][r] = mn;
        fsc[i][r] = __expf(m_st[i][r] - mn);
        m_st[i][r] = mn;
      }
#pragma unroll
    for (int i = 0; i < 2; i++)
#pragma unroll
      for (int r = 0; r < 4; r++) {
        float ls = 0.f;
#pragma unroll
        for (int j = 0; j < 4; j++) {
          float p = __expf(sa[i][j][r] - mnew[i][r]);
          sa[i][j][r] = p;
          ls += p;
        }
        ls = rsum16(ls);
        l_st[i][r] = l_st[i][r] * fsc[i][r] + ls;
      }
#pragma unroll
    for (int i = 0; i < 2; i++)
#pragma unroll
      for (int j = 0; j < 4; j++)
#pragma unroll
        for (int r = 0; r < 4; r++) acc_o[i][j][r] *= fsc[i][r];

#pragma unroll
    for (int i = 0; i < 2; i++)
#pragma unroll
      for (int j = 0; j < 4; j++)
#pragma unroll
        for (int r = 0; r < 4; r++) {
          int qrl = lg * 4 + r;
          int idx = (i * 16 + qrl) * 64 + (((j * 2 + (lr >> 3)) ^ (qrl & 7)) * 8) + (lr & 7);
          Ps[w][idx] = f2bf(sa[i][j][r]);
        }

#pragma unroll
    for (int kk = 0; kk < 2; kk++) {
      short8 pf[2], vf[4];
#pragma unroll
      for (int i = 0; i < 2; i++)
        pf[i] = *(const short8*)&Ps[w][(i * 16 + lr) * 64 + ((kk * 4 + lg) ^ (lr & 7)) * 8];
#pragma unroll
      for (int j = 0; j < 4; j++)
        vf[j] = *(const short8*)&VsL[buf][(j * 16 + lr) * 64 + ((kk * 4 + lg) ^ (lr & 7)) * 8];
#pragma unroll
      for (int i = 0; i < 2; i++)
#pragma unroll
        for (int j = 0; j < 4; j++) MFMA(acc_o[i][j], pf[i], vf[j]);
    }

    __syncthreads();
    buf ^= 1;
  }

  float inv[2][4];
#pragma unroll
  for (int i = 0; i < 2; i++)
#pragma unroll
    for (int r = 0; r < 4; r++) inv[i][r] = 1.0f / l_st[i][r];
#pragma unroll
  for (int i = 0; i < 2; i++)
#pragma unroll
    for (int j = 0; j < 4; j++)
#pragma unroll
      for (int r = 0; r < 4; r++) {
        size_t row = qmin + i * 16 + lg * 4 + r;
        Og[row * ldo + h * 64 + j * 16 + lr] = f2bf(acc_o[i][j][r] * inv[i][r]);
      }
}

// rmsnorm; mode 0: plain, 1: fold x+p1+p2, 2: embed-init (emb[id]+pos)
__global__ __launch_bounds__(256) void rmsnorm_fold(
    const float* __restrict__ xin,
    const float* __restrict__ p1, const float* __restrict__ p2,
    const int* __restrict__ ids, const float* __restrict__ emb,
    const float* __restrict__ pos,
    unsigned short* __restrict__ o1, float* __restrict__ xout, int mode)
{
  int row = blockIdx.x;
  int tid = threadIdx.x;
  size_t base = (size_t)row * DMODEL + tid * 4;
  float4 val;
  if (mode == 2) {
    int id = ids[row];
    float4 e = *(const float4*)(emb + (size_t)id * DMODEL + tid * 4);
    float4 p = *(const float4*)(pos + base);
    val.x = e.x + p.x; val.y = e.y + p.y; val.z = e.z + p.z; val.w = e.w + p.w;
    *(float4*)(xout + base) = val;
  } else if (mode == 1) {
    float4 a = *(const float4*)(xin + base);
    float4 b = *(const float4*)(p1 + base);
    float4 c = *(const float4*)(p2 + base);
    val.x = a.x + b.x + c.x; val.y = a.y + b.y + c.y;
    val.z = a.z + b.z + c.z; val.w = a.w + b.w + c.w;
    *(float4*)(xout + base) = val;
  } else {
    val = *(const float4*)(xin + base);
  }
  float ss = val.x * val.x + val.y * val.y + val.z * val.z + val.w * val.w;
#pragma unroll
  for (int o = 32; o > 0; o >>= 1) ss += __shfl_xor(ss, o);
  __shared__ float red[4];
  if ((tid & 63) == 0) red[tid >> 6] = ss;
  __syncthreads();
  ss = red[0] + red[1] + red[2] + red[3];
  float inv = rsqrtf(ss / DMODEL + 1e-6f);
  ushort4 o;
  o.x = f2bf(val.x * inv); o.y = f2bf(val.y * inv);
  o.z = f2bf(val.z * inv); o.w = f2bf(val.w * inv);
  *(ushort4*)(o1 + base) = o;
}

// one launch: weight prep for ALL layers; LN scales folded into weights
__global__ __launch_bounds__(256) void prep_weights_all(
    const float* __restrict__ wq_, const float* __restrict__ wk_,
    const float* __restrict__ wv_, const float* __restrict__ wo_,
    const float* __restrict__ gw_, const float* __restrict__ vw_,
    const float* __restrict__ fw_, const float* __restrict__ ln1_,
    const float* __restrict__ ln2_,
    unsigned short* __restrict__ qkvw_, unsigned short* __restrict__ wft_,
    unsigned short* __restrict__ gvt_)
{
  __shared__ float t0[32][33], t1[32][33];
  const int li = blockIdx.x / 12288;
  int bid = blockIdx.x % 12288;
  int tx = threadIdx.x, ty = threadIdx.y;
  const float* wq = wq_ + (size_t)li * 1024 * 1024;
  const float* wk = wk_ + (size_t)li * 1024 * 1024;
  const float* wv = wv_ + (size_t)li * 1024 * 1024;
  const float* wo = wo_ + (size_t)li * 1024 * 1024;
  const float* gw = gw_ + (size_t)li * 1024 * 4096;
  const float* vw = vw_ + (size_t)li * 1024 * 4096;
  const float* fw = fw_ + (size_t)li * 4096 * 1024;
  const float* s1 = ln1_ + (size_t)li * 1024;
  const float* s2 = ln2_ + (size_t)li * 1024;
  unsigned short* qkvw = qkvw_ + (size_t)li * 3 * 1024 * 1024;
  unsigned short* wft = wft_ + (size_t)li * 1024 * 5120;
  unsigned short* gvt = gvt_ + (size_t)li * 2 * 4096 * 1024;

  if (bid < 4096) {
    int j = bid >> 10, tile = bid & 1023;
    int c0 = (tile & 31) * 32, r0 = (tile >> 5) * 32;
    const float* src = j == 0 ? wq : j == 1 ? wk : j == 2 ? wv : wo;
#pragma unroll
    for (int k = 0; k < 32; k += 8)
      t0[ty + k][tx] = src[(size_t)(r0 + ty + k) * 1024 + c0 + tx];
    __syncthreads();
    if (j < 3) {
      unsigned short* dst = qkvw + (size_t)j * 1024 * 1024;
      float sc = s1[r0 + tx];
#pragma unroll
      for (int k = 0; k < 32; k += 8)
        dst[(size_t)(c0 + ty + k) * 1024 + r0 + tx] = f2bf(t0[tx][ty + k] * sc);
    } else {
#pragma unroll
      for (int k = 0; k < 32; k += 8)
        wft[(size_t)(c0 + ty + k) * 5120 + r0 + tx] = f2bf(t0[tx][ty + k]);
    }
  } else if (bid < 8192) {
    int tile = bid - 4096;
    int c0 = (tile & 31) * 32;
    int r0 = (tile >> 5) * 32;
#pragma unroll
    for (int k = 0; k < 32; k += 8)
      t0[ty + k][tx] = fw[(size_t)(r0 + ty + k) * 1024 + c0 + tx];
    __syncthreads();
#pragma unroll
    for (int k = 0; k < 32; k += 8)
      wft[(size_t)(c0 + ty + k) * 5120 + 1024 + r0 + tx] = f2bf(t0[tx][ty + k]);
  } else {
    int tile = bid - 8192;
    int c0 = (tile & 127) * 32;
    int d0 = (tile >> 7) * 32;
#pragma unroll
    for (int k = 0; k < 32; k += 8) {
      t0[ty + k][tx] = gw[(size_t)(d0 + ty + k) * 4096 + c0 + tx];
      t1[ty + k][tx] = vw[(size_t)(d0 + ty + k) * 4096 + c0 + tx];
    }
    __syncthreads();
    float sc = s2[d0 + tx];
#pragma unroll
    for (int k = 0; k < 32; k += 8) {
      gvt[(size_t)(2 * (c0 + ty + k)) * 1024 + d0 + tx] = f2bf(t0[tx][ty + k] * sc);
      gvt[(size_t)(2 * (c0 + ty + k) + 1) * 1024 + d0 + tx] = f2bf(t1[tx][ty + k] * sc);
    }
  }
}

// embb[v][d] = bf16(embed[v][d] * lnf[d])  (final-LN folded into tied embed)
__global__ __launch_bounds__(256) void convert_embb(
    const float* __restrict__ in, const float* __restrict__ lnf,
    unsigned short* __restrict__ out, size_t n)
{
  size_t i = ((size_t)blockIdx.x * 256 + threadIdx.x) * 4;
  if (i + 3 < n) {
    float4 v = *(const float4*)(in + i);
    int d = (int)(i & 1023);
    out[i] = f2bf(v.x * lnf[d]);
    out[i + 1] = f2bf(v.y * lnf[d + 1]);
    out[i + 2] = f2bf(v.z * lnf[d + 2]);
    out[i + 3] = f2bf(v.w * lnf[d + 3]);
  }
}

extern "C" void kernel_launch(void* const* d_in, const int* in_sizes, int n_in,
                              void* d_out, int out_size, void* d_ws, size_t ws_size,
                              hipStream_t stream)
{
  const int L = L_SEQ, D = DMODEL, F = FFN_F, V = VOCAB;
  const int* ids = (const int*)d_in[0];
  const float* embed = (const float*)d_in[1];
  const float* pos = (const float*)d_in[2];
  const float* wq = (const float*)d_in[3];
  const float* wk = (const float*)d_in[4];
  const float* wv = (const float*)d_in[5];
  const float* wo = (const float*)d_in[6];
  const float* gatew = (const float*)d_in[7];
  const float* valw = (const float*)d_in[8];
  const float* ffow = (const float*)d_in[9];
  const float* ln1 = (const float*)d_in[10];
  const float* ln2 = (const float*)d_in[11];
  const float* lnf = (const float*)d_in[12];

  char* ws = (char*)d_ws;
  size_t off = 0;
  auto alloc = [&](size_t bytes) -> void* {
    void* p = ws + off;
    off += (bytes + 255) & ~(size_t)255;
    return p;
  };
  float* x = (float*)alloc((size_t)L * D * 4);
  float* pbuf = (float*)alloc((size_t)2 * L * D * 4);
  unsigned short* xhat = (unsigned short*)alloc((size_t)L * D * 2);
  unsigned short* qkvb = (unsigned short*)alloc((size_t)L * 2 * D * 2);  // Q|K
  unsigned short* vtb = (unsigned short*)alloc((size_t)L * D * 2);       // V^T
  unsigned short* ohb = (unsigned short*)alloc((size_t)L * 5120 * 2);
  unsigned short* qkvw = (unsigned short*)alloc((size_t)NLAYER * 3 * D * D * 2);
  unsigned short* gvt = (unsigned short*)alloc((size_t)NLAYER * 2 * F * D * 2);
  unsigned short* wft = (unsigned short*)alloc((size_t)NLAYER * D * 5120 * 2);
  unsigned short* embb = (unsigned short*)alloc((size_t)V * D * 2);

  dim3 blk(256);
  dim3 blk512(512);
  dim3 blkT(32, 8);

  convert_embb<<<(unsigned)((size_t)V * D / 1024), blk, 0, stream>>>(
      embed, lnf, embb, (size_t)V * D);
  prep_weights_all<<<NLAYER * 12288, blkT, 0, stream>>>(
      wq, wk, wv, wo, gatew, valw, ffow, ln1, ln2, qkvw, wft, gvt);

  for (int i = 0; i < NLAYER; i++) {
    unsigned short* qkvw_l = qkvw + (size_t)i * 3 * D * D;
    unsigned short* gvt_l = gvt + (size_t)i * 2 * F * D;
    unsigned short* wft_l = wft + (size_t)i * D * 5120;

    // layer 0: embed-init (mode 2); others: fold residual partials (mode 1)
    rmsnorm_fold<<<L, blk, 0, stream>>>(
        i == 0 ? nullptr : x, pbuf, pbuf + (size_t)L * D,
        ids, embed, pos, xhat, x, i == 0 ? 2 : 1);

    // QKV projection; writes Q|K to qkvb (ld 2048) and V^T to vtb directly
    gemm_fast<E_QKVT><<<dim3(24 * 16), blk, 0, stream>>>(
        xhat, qkvw_l, qkvb, vtb, L, 3 * D, D, D, D, 2 * D, 1.0f, 24);

    flash_attn<<<dim3(512), dim3(128), 0, stream>>>(
        qkvb, qkvb + D, vtb, ohb, 2 * D, 5120);

    // swiglu: exactly 256 blocks = 1 full wave
    gemm8p<E_SWIGLU><<<dim3(8 * 32), blk512, 0, stream>>>(
        xhat, gvt_l, ohb + 1024, L, 2 * F, D, D, D, 5120, 1.0f, 8);

    // combined output GEMM: [O | swiglu] * [wo^T ; ffo^T], split-K=2 partials
    gemm_fast<E_PART><<<dim3(8 * 16, 1, 2), blk, 0, stream>>>(
        ohb, wft_l, pbuf, nullptr, L, D, 5120, 5120, 5120, D, 1.0f, 8);
  }

  rmsnorm_fold<<<L, blk, 0, stream>>>(x, pbuf, pbuf + (size_t)L * D,
                                      ids, embed, pos, xhat, x, 1);
  gemm8p<E_F32><<<dim3(8 * 125), blk512, 0, stream>>>(
      xhat, embb, d_out, L, V, D, D, D, V, 1.0f, 8);
}

// Round 12
// 1223.619 us; speedup vs baseline: 1.0143x; 1.0143x over previous
//
#include <hip/hip_runtime.h>
#include <cstdint>
#include <cstddef>

#define L_SEQ 2048
#define DMODEL 1024
#define NHEAD 16
#define DHEAD 64
#define FFN_F 4096
#define VOCAB 32000
#define NLAYER 4

typedef __attribute__((ext_vector_type(8))) short short8;
typedef __attribute__((ext_vector_type(4))) float f32x4;

__device__ __forceinline__ unsigned short f2bf(float f) {
  unsigned int u = __float_as_uint(f);
  u += 0x7fffu + ((u >> 16) & 1u);
  return (unsigned short)(u >> 16);
}
__device__ __forceinline__ float b2f(unsigned short h) {
  return __uint_as_float(((unsigned int)h) << 16);
}

__device__ __forceinline__ void glds16(const unsigned short* g, unsigned short* l) {
  __builtin_amdgcn_global_load_lds(
      (const __attribute__((address_space(1))) unsigned int*)g,
      (__attribute__((address_space(3))) unsigned int*)l, 16, 0, 0);
}

__device__ __forceinline__ float rmax16(float v) {
  v = fmaxf(v, __shfl_xor(v, 1));
  v = fmaxf(v, __shfl_xor(v, 2));
  v = fmaxf(v, __shfl_xor(v, 4));
  v = fmaxf(v, __shfl_xor(v, 8));
  return v;
}
__device__ __forceinline__ float rsum16(float v) {
  v += __shfl_xor(v, 1);
  v += __shfl_xor(v, 2);
  v += __shfl_xor(v, 4);
  v += __shfl_xor(v, 8);
  return v;
}

#define MFMA(ACC, AF, BF) \
  ACC = __builtin_amdgcn_mfma_f32_16x16x32_bf16(AF, BF, ACC, 0, 0, 0)

enum { E_F32 = 0, E_BF16 = 1, E_SWIGLU = 2, E_PART = 3 };

// ============ 8-phase 256x256 GEMM (T2+T3+T4+T5), 512 thr, BK=64 ============
template <int EPI>
__global__ __launch_bounds__(512, 2) void gemm8p(
    const unsigned short* __restrict__ A, const unsigned short* __restrict__ B,
    void* __restrict__ Cg, int M, int N, int K, int lda, int ldb, int ldc,
    float alpha, int nby)
{
  const int nwg = gridDim.x;
  const int orig = blockIdx.x;
  const int q = nwg >> 3, r = nwg & 7;
  const int xcd = orig & 7, rest = orig >> 3;
  const int wgid = (xcd < r ? xcd * (q + 1) : r * (q + 1) + (xcd - r) * q) + rest;
  const int by = wgid % nby, bx = wgid / nby;
  const int mb = by * 256, nb = bx * 256;

  __shared__ __align__(16) unsigned short As_[2][256 * 64];
  __shared__ __align__(16) unsigned short Bs_[2][256 * 64];

  const int tid = threadIdx.x;
  const int lane = tid & 63;
  const int w = tid >> 6;
  const int wm = (w >> 2) * 128;
  const int wn = (w & 3) * 64;
  const int lr = lane & 15;
  const int lg = lane >> 4;
  const int srow = lane >> 3;
  const int scol = ((lane & 7) ^ srow) * 8;
  const int slot0 = (lg ^ (lr & 7)) * 8;
  const int slot1 = ((4 + lg) ^ (lr & 7)) * 8;

  f32x4 acc[8][4];
#pragma unroll
  for (int i = 0; i < 8; i++)
#pragma unroll
    for (int j = 0; j < 4; j++) acc[i][j] = (f32x4){0.f, 0.f, 0.f, 0.f};

  const unsigned short* Ab = A + (size_t)(mb + srow) * lda + scol;
  const unsigned short* Bb = B + (size_t)(nb + srow) * ldb + scol;

  auto stageA = [&](int t, int R) {
    const int s = t & 1, kb = t << 6;
#pragma unroll
    for (int c = 0; c < 2; c++) {
      int cid = w * 2 + c;
      int rb = ((cid >> 3) << 7) + R * 64 + ((cid & 7) << 3);
      glds16(Ab + (size_t)rb * lda + kb, &As_[s][rb * 64]);
    }
  };
  auto stageB = [&](int t, int R) {
    const int s = t & 1, kb = t << 6;
#pragma unroll
    for (int c = 0; c < 2; c++) {
      int cid = w * 2 + c;
      int rb = ((cid >> 2) << 6) + R * 32 + ((cid & 3) << 3);
      glds16(Bb + (size_t)rb * ldb + kb, &Bs_[s][rb * 64]);
    }
  };

  const int nk = K >> 6;
  stageA(0, 0); stageA(0, 1); stageB(0, 0); stageB(0, 1);
  stageA(1, 0); stageB(1, 0); stageB(1, 1);
  asm volatile("s_waitcnt vmcnt(6)" ::: "memory");
  __builtin_amdgcn_s_barrier();

  short8 a[4][2], b0[2][2], b1[2][2];
#pragma unroll
  for (int j = 0; j < 2; j++) {
    b0[j][0] = *(const short8*)&Bs_[0][(wn + j * 16 + lr) * 64 + slot0];
    b0[j][1] = *(const short8*)&Bs_[0][(wn + j * 16 + lr) * 64 + slot1];
  }

  for (int t = 0; t < nk; ++t) {
    const int s = t & 1;
    const unsigned short* Asb = &As_[s][0];
    const unsigned short* Bsb = &Bs_[s][0];

    // phase 1: read A-low; stage A-R2(t+1); MFMA (m-lo x n-lo)
#pragma unroll
    for (int i = 0; i < 4; i++) {
      a[i][0] = *(const short8*)&Asb[(wm + i * 16 + lr) * 64 + slot0];
      a[i][1] = *(const short8*)&Asb[(wm + i * 16 + lr) * 64 + slot1];
    }
    if (t + 1 < nk) stageA(t + 1, 1);
    __builtin_amdgcn_s_barrier();
    __builtin_amdgcn_s_setprio(1);
#pragma unroll
    for (int kk = 0; kk < 2; kk++)
#pragma unroll
      for (int i = 0; i < 4; i++)
#pragma unroll
        for (int j = 0; j < 2; j++) MFMA(acc[i][j], a[i][kk], b0[j][kk]);
    __builtin_amdgcn_s_setprio(0);
    __builtin_amdgcn_s_barrier();

    // phase 2: read B-high; stage A-R1(t+2); MFMA (m-lo x n-hi)
#pragma unroll
    for (int j = 0; j < 2; j++) {
      b1[j][0] = *(const short8*)&Bsb[(wn + 32 + j * 16 + lr) * 64 + slot0];
      b1[j][1] = *(const short8*)&Bsb[(wn + 32 + j * 16 + lr) * 64 + slot1];
    }
    if (t + 2 < nk) stageA(t + 2, 0);
    __builtin_amdgcn_s_barrier();
    __builtin_amdgcn_s_setprio(1);
#pragma unroll
    for (int kk = 0; kk < 2; kk++)
#pragma unroll
      for (int i = 0; i < 4; i++)
#pragma unroll
        for (int j = 0; j < 2; j++) MFMA(acc[i][2 + j], a[i][kk], b1[j][kk]);
    __builtin_amdgcn_s_setprio(0);
    __builtin_amdgcn_s_barrier();

    // phase 3: read A-high; stage B-R1(t+2); MFMA (m-hi x n-hi)
#pragma unroll
    for (int i = 0; i < 4; i++) {
      a[i][0] = *(const short8*)&Asb[(wm + 64 + i * 16 + lr) * 64 + slot0];
      a[i][1] = *(const short8*)&Asb[(wm + 64 + i * 16 + lr) * 64 + slot1];
    }
    if (t + 2 < nk) stageB(t + 2, 0);
    __builtin_amdgcn_s_barrier();
    __builtin_amdgcn_s_setprio(1);
#pragma unroll
    for (int kk = 0; kk < 2; kk++)
#pragma unroll
      for (int i = 0; i < 4; i++)
#pragma unroll
        for (int j = 0; j < 2; j++) MFMA(acc[4 + i][2 + j], a[i][kk], b1[j][kk]);
    __builtin_amdgcn_s_setprio(0);
    __builtin_amdgcn_s_barrier();

    // phase 4: stage B-R2(t+2); MFMA (m-hi x n-lo); counted vmcnt; tail b0 read
    if (t + 2 < nk) stageB(t + 2, 1);
    __builtin_amdgcn_s_barrier();
    __builtin_amdgcn_s_setprio(1);
#pragma unroll
    for (int kk = 0; kk < 2; kk++)
#pragma unroll
      for (int i = 0; i < 4; i++)
#pragma unroll
        for (int j = 0; j < 2; j++) MFMA(acc[4 + i][j], a[i][kk], b0[j][kk]);
    __builtin_amdgcn_s_setprio(0);
    if (t + 2 < nk) {
      asm volatile("s_waitcnt vmcnt(6)" ::: "memory");
    } else {
      asm volatile("s_waitcnt vmcnt(0)" ::: "memory");
    }
    __builtin_amdgcn_s_barrier();
    if (t + 1 < nk) {
      const unsigned short* Bn = &Bs_[s ^ 1][0];
#pragma unroll
      for (int j = 0; j < 2; j++) {
        b0[j][0] = *(const short8*)&Bn[(wn + j * 16 + lr) * 64 + slot0];
        b0[j][1] = *(const short8*)&Bn[(wn + j * 16 + lr) * 64 + slot1];
      }
    }
  }

#pragma unroll
  for (int i = 0; i < 8; i++) {
#pragma unroll
    for (int j = 0; j < 4; j++) {
      int oc = nb + wn + 16 * j + lr;
#pragma unroll
      for (int r4 = 0; r4 < 4; r4++) {
        int orow = mb + wm + 16 * i + lg * 4 + r4;
        float v = acc[i][j][r4] * alpha;
        if (EPI == E_F32) {
          ((float*)Cg)[(size_t)orow * ldc + oc] = v;
        } else if (EPI == E_BF16) {
          ((unsigned short*)Cg)[(size_t)orow * ldc + oc] = f2bf(v);
        } else if (EPI == E_SWIGLU) {
          float other = __shfl_xor(v, 1);
          float g = (lane & 1) ? other : v;
          float vv = (lane & 1) ? v : other;
          float sw = g / (1.0f + expf(-g)) * vv;
          if (!(lane & 1))
            ((unsigned short*)Cg)[(size_t)orow * ldc + (oc >> 1)] = f2bf(sw);
        }
      }
    }
  }
}

// ============ 128x128 2-phase GEMM ==========================================
template <int EPI>
__global__ __launch_bounds__(256) void gemm_fast(
    const unsigned short* __restrict__ A, const unsigned short* __restrict__ B,
    void* __restrict__ Cg, int M, int N, int K, int lda, int ldb, int ldc,
    float alpha, int nbx)
{
  const int nwg = gridDim.x;
  const int orig = blockIdx.x;
  const int q = nwg >> 3, r = nwg & 7;
  const int xcd = orig & 7, rest = orig >> 3;
  const int wgid = (xcd < r ? xcd * (q + 1) : r * (q + 1) + (xcd - r) * q) + rest;
  const int bx = wgid % nbx, by = wgid / nbx;
  const int mb = by * 128;
  const int nb = bx * 128;

  const int Keff = (EPI == E_PART) ? (K >> 1) : K;
  const int koff = (EPI == E_PART) ? blockIdx.z * Keff : 0;

  __shared__ __align__(16) unsigned short As[2][128 * 64];
  __shared__ __align__(16) unsigned short Bs[2][128 * 64];

  const int tid = threadIdx.x;
  const int lane = tid & 63;
  const int wave = tid >> 6;
  const int wm = (wave >> 1) * 64;
  const int wn = (wave & 1) * 64;
  const int lr = lane & 15;
  const int lg = lane >> 4;

  const int srow = lane >> 3;
  const int scol = ((lane & 7) ^ srow) * 8;

  f32x4 acc[4][4];
#pragma unroll
  for (int i = 0; i < 4; i++)
#pragma unroll
    for (int j = 0; j < 4; j++) acc[i][j] = (f32x4){0.f, 0.f, 0.f, 0.f};

  const unsigned short* Abase = A + (size_t)(mb + wave * 32 + srow) * lda + koff + scol;
  const unsigned short* Bbase = B + (size_t)(nb + wave * 32 + srow) * ldb + koff + scol;

  auto stage = [&](int kb, int b) {
#pragma unroll
    for (int c = 0; c < 4; c++)
      glds16(Abase + (size_t)(c * 8) * lda + kb, &As[b][(wave * 32 + c * 8) * 64]);
#pragma unroll
    for (int c = 0; c < 4; c++)
      glds16(Bbase + (size_t)(c * 8) * ldb + kb, &Bs[b][(wave * 32 + c * 8) * 64]);
  };

  stage(0, 0);
  __syncthreads();
  int cur = 0;
  const int nk = Keff >> 6;

  for (int t = 0; t < nk; ++t) {
    if (t + 1 < nk) stage((t + 1) << 6, cur ^ 1);

    short8 af[2][4], bfb[2][4];
#pragma unroll
    for (int h = 0; h < 2; h++) {
      const int swz = ((h * 4 + lg) ^ (lr & 7)) * 8;
#pragma unroll
      for (int i = 0; i < 4; i++) {
        af[h][i] = *(const short8*)&As[cur][(wm + 16 * i + lr) * 64 + swz];
        bfb[h][i] = *(const short8*)&Bs[cur][(wn + 16 * i + lr) * 64 + swz];
      }
    }
#pragma unroll
    for (int h = 0; h < 2; h++)
#pragma unroll
      for (int i = 0; i < 4; i++)
#pragma unroll
        for (int j = 0; j < 4; j++) MFMA(acc[i][j], af[h][i], bfb[h][j]);

    __syncthreads();
    cur ^= 1;
  }

#pragma unroll
  for (int i = 0; i < 4; i++) {
#pragma unroll
    for (int j = 0; j < 4; j++) {
      int oc = nb + wn + 16 * j + lr;
#pragma unroll
      for (int r4 = 0; r4 < 4; r4++) {
        int orow = mb + wm + 16 * i + lg * 4 + r4;
        float v = acc[i][j][r4] * alpha;
        if (EPI == E_F32) {
          ((float*)Cg)[(size_t)orow * ldc + oc] = v;
        } else if (EPI == E_BF16) {
          ((unsigned short*)Cg)[(size_t)orow * ldc + oc] = f2bf(v);
        } else {  // E_PART
          float* C = (float*)Cg + (size_t)blockIdx.z * ((size_t)L_SEQ * DMODEL);
          C[(size_t)orow * ldc + oc] = v;
        }
      }
    }
  }
}

// ---------------- fused flash attention (balanced, QBLK=64, 2 waves) --------
__global__ __launch_bounds__(128) void flash_attn(
    const unsigned short* __restrict__ Qg, const unsigned short* __restrict__ Kg,
    const unsigned short* __restrict__ Vt, unsigned short* __restrict__ Og,
    int ldq, int ldo)
{
  const int bid = blockIdx.x;
  const int slot = bid & 255, ph = bid >> 8;
  const int h = slot >> 4;
  const int qs = slot & 15;
  const int qb = ph ? (31 - qs) : qs;

  const int tid = threadIdx.x;
  const int lane = tid & 63;
  const int w = tid >> 6;
  const int lr = lane & 15;
  const int lg = lane >> 4;

  __shared__ __align__(16) unsigned short KsL[2][64 * 64];
  __shared__ __align__(16) unsigned short VsL[2][64 * 64];
  __shared__ __align__(16) unsigned short Ps[2][32 * 64];

  const int srow = lane >> 3;
  const int scol = ((lane & 7) ^ srow) * 8;

  short8 qf[2][2];
#pragma unroll
  for (int i = 0; i < 2; i++)
#pragma unroll
    for (int kk = 0; kk < 2; kk++)
      qf[i][kk] = *(const short8*)(Qg +
          (size_t)(qb * 64 + w * 32 + i * 16 + lr) * ldq + h * 64 + kk * 32 + lg * 8);

  f32x4 acc_o[2][4];
  float m_st[2][4], l_st[2][4];
#pragma unroll
  for (int i = 0; i < 2; i++)
#pragma unroll
    for (int j = 0; j < 4; j++) acc_o[i][j] = (f32x4){0.f, 0.f, 0.f, 0.f};
#pragma unroll
  for (int i = 0; i < 2; i++)
#pragma unroll
    for (int r = 0; r < 4; r++) { m_st[i][r] = -1e30f; l_st[i][r] = 0.f; }

  const int ntiles = qb + 1;
  const int qmin = qb * 64 + w * 32;

  auto stage = [&](int t, int buf) {
#pragma unroll
    for (int c = 0; c < 4; c++) {
      int row = w * 32 + c * 8 + srow;
      glds16(Kg + (size_t)(t * 64 + row) * ldq + h * 64 + scol,
             &KsL[buf][row * 64]);
      glds16(Vt + (size_t)(h * 64 + row) * L_SEQ + t * 64 + scol,
             &VsL[buf][row * 64]);
    }
  };

  stage(0, 0);
  __syncthreads();
  int buf = 0;

  for (int t = 0; t < ntiles; t++) {
    if (t + 1 < ntiles) stage(t + 1, buf ^ 1);

    f32x4 sa[2][4];
#pragma unroll
    for (int i = 0; i < 2; i++)
#pragma unroll
      for (int j = 0; j < 4; j++) sa[i][j] = (f32x4){0.f, 0.f, 0.f, 0.f};
#pragma unroll
    for (int kk = 0; kk < 2; kk++) {
      short8 kf[4];
#pragma unroll
      for (int j = 0; j < 4; j++)
        kf[j] = *(const short8*)&KsL[buf][(j * 16 + lr) * 64 + ((kk * 4 + lg) ^ (lr & 7)) * 8];
#pragma unroll
      for (int i = 0; i < 2; i++)
#pragma unroll
        for (int j = 0; j < 4; j++) MFMA(sa[i][j], qf[i][kk], kf[j]);
    }

    const bool diag = (t * 64 + 63) > qmin;
#pragma unroll
    for (int i = 0; i < 2; i++)
#pragma unroll
      for (int j = 0; j < 4; j++)
#pragma unroll
        for (int r = 0; r < 4; r++) {
          float s = sa[i][j][r] * 0.125f;
          if (diag) {
            int kg = t * 64 + j * 16 + lr;
            int qg = qmin + i * 16 + lg * 4 + r;
            if (kg > qg) s = -1e30f;
          }
          sa[i][j][r] = s;
        }

    float fsc[2][4], mnew[2][4];
#pragma unroll
    for (int i = 0; i < 2; i++)
#pragma unroll
      for (int r = 0; r < 4; r++) {
        float mx = fmaxf(fmaxf(sa[i][0][r], sa[i][1][r]), fmaxf(sa[i][2][r], sa[i][3][r]));
        mx = rmax16(mx);
        float mn = fmaxf(m_st[i][r], mx);
        mnew[i][r] = mn;
        fsc[i][r] = __expf(m_st[i][r] - mn);
        m_st[i][r] = mn;
      }
#pragma unroll
    for (int i = 0; i < 2; i++)
#pragma unroll
      for (int r = 0; r < 4; r++) {
        float ls = 0.f;
#pragma unroll
        for (int j = 0; j < 4; j++) {
          float p = __expf(sa[i][j][r] - mnew[i][r]);
          sa[i][j][r] = p;
          ls += p;
        }
        ls = rsum16(ls);
        l_st[i][r] = l_st[i][r] * fsc[i][r] + ls;
      }
#pragma unroll
    for (int i = 0; i < 2; i++)
#pragma unroll
      for (int j = 0; j < 4; j++)
#pragma unroll
        for (int r = 0; r < 4; r++) acc_o[i][j][r] *= fsc[i][r];

#pragma unroll
    for (int i = 0; i < 2; i++)
#pragma unroll
      for (int j = 0; j < 4; j++)
#pragma unroll
        for (int r = 0; r < 4; r++) {
          int qrl = lg * 4 + r;
          int idx = (i * 16 + qrl) * 64 + (((j * 2 + (lr >> 3)) ^ (qrl & 7)) * 8) + (lr & 7);
          Ps[w][idx] = f2bf(sa[i][j][r]);
        }

#pragma unroll
    for (int kk = 0; kk < 2; kk++) {
      short8 pf[2], vf[4];
#pragma unroll
      for (int i = 0; i < 2; i++)
        pf[i] = *(const short8*)&Ps[w][(i * 16 + lr) * 64 + ((kk * 4 + lg) ^ (lr & 7)) * 8];
#pragma unroll
      for (int j = 0; j < 4; j++)
        vf[j] = *(const short8*)&VsL[buf][(j * 16 + lr) * 64 + ((kk * 4 + lg) ^ (lr & 7)) * 8];
#pragma unroll
      for (int i = 0; i < 2; i++)
#pragma unroll
        for (int j = 0; j < 4; j++) MFMA(acc_o[i][j], pf[i], vf[j]);
    }

    __syncthreads();
    buf ^= 1;
  }

  float inv[2][4];
#pragma unroll
  for (int i = 0; i < 2; i++)
#pragma unroll
    for (int r = 0; r < 4; r++) inv[i][r] = 1.0f / l_st[i][r];
#pragma unroll
  for (int i = 0; i < 2; i++)
#pragma unroll
    for (int j = 0; j < 4; j++)
#pragma unroll
      for (int r = 0; r < 4; r++) {
        size_t row = qmin + i * 16 + lg * 4 + r;
        Og[row * ldo + h * 64 + j * 16 + lr] = f2bf(acc_o[i][j][r] * inv[i][r]);
      }
}

// rmsnorm; mode 1: fold x+p1+p2, 2: embed-init (emb[id]+pos)
__global__ __launch_bounds__(256) void rmsnorm_fold(
    const float* __restrict__ xin,
    const float* __restrict__ p1, const float* __restrict__ p2,
    const int* __restrict__ ids, const float* __restrict__ emb,
    const float* __restrict__ pos,
    unsigned short* __restrict__ o1, float* __restrict__ xout, int mode)
{
  int row = blockIdx.x;
  int tid = threadIdx.x;
  size_t base = (size_t)row * DMODEL + tid * 4;
  float4 val;
  if (mode == 2) {
    int id = ids[row];
    float4 e = *(const float4*)(emb + (size_t)id * DMODEL + tid * 4);
    float4 p = *(const float4*)(pos + base);
    val.x = e.x + p.x; val.y = e.y + p.y; val.z = e.z + p.z; val.w = e.w + p.w;
    *(float4*)(xout + base) = val;
  } else {
    float4 a = *(const float4*)(xin + base);
    float4 b = *(const float4*)(p1 + base);
    float4 c = *(const float4*)(p2 + base);
    val.x = a.x + b.x + c.x; val.y = a.y + b.y + c.y;
    val.z = a.z + b.z + c.z; val.w = a.w + b.w + c.w;
    *(float4*)(xout + base) = val;
  }
  float ss = val.x * val.x + val.y * val.y + val.z * val.z + val.w * val.w;
#pragma unroll
  for (int o = 32; o > 0; o >>= 1) ss += __shfl_xor(ss, o);
  __shared__ float red[4];
  if ((tid & 63) == 0) red[tid >> 6] = ss;
  __syncthreads();
  ss = red[0] + red[1] + red[2] + red[3];
  float inv = rsqrtf(ss / DMODEL + 1e-6f);
  ushort4 o;
  o.x = f2bf(val.x * inv); o.y = f2bf(val.y * inv);
  o.z = f2bf(val.z * inv); o.w = f2bf(val.w * inv);
  *(ushort4*)(o1 + base) = o;
}

// one launch: weight prep for ALL layers; LN scales folded into weights
__global__ __launch_bounds__(256) void prep_weights_all(
    const float* __restrict__ wq_, const float* __restrict__ wk_,
    const float* __restrict__ wv_, const float* __restrict__ wo_,
    const float* __restrict__ gw_, const float* __restrict__ vw_,
    const float* __restrict__ fw_, const float* __restrict__ ln1_,
    const float* __restrict__ ln2_,
    unsigned short* __restrict__ qkvw_, unsigned short* __restrict__ wft_,
    unsigned short* __restrict__ gvt_)
{
  __shared__ float t0[32][33], t1[32][33];
  const int li = blockIdx.x / 12288;
  int bid = blockIdx.x % 12288;
  int tx = threadIdx.x, ty = threadIdx.y;
  const float* wq = wq_ + (size_t)li * 1024 * 1024;
  const float* wk = wk_ + (size_t)li * 1024 * 1024;
  const float* wv = wv_ + (size_t)li * 1024 * 1024;
  const float* wo = wo_ + (size_t)li * 1024 * 1024;
  const float* gw = gw_ + (size_t)li * 1024 * 4096;
  const float* vw = vw_ + (size_t)li * 1024 * 4096;
  const float* fw = fw_ + (size_t)li * 4096 * 1024;
  const float* s1 = ln1_ + (size_t)li * 1024;
  const float* s2 = ln2_ + (size_t)li * 1024;
  unsigned short* qkvw = qkvw_ + (size_t)li * 3 * 1024 * 1024;
  unsigned short* wft = wft_ + (size_t)li * 1024 * 5120;
  unsigned short* gvt = gvt_ + (size_t)li * 2 * 4096 * 1024;

  if (bid < 4096) {
    int j = bid >> 10, tile = bid & 1023;
    int c0 = (tile & 31) * 32, r0 = (tile >> 5) * 32;
    const float* src = j == 0 ? wq : j == 1 ? wk : j == 2 ? wv : wo;
#pragma unroll
    for (int k = 0; k < 32; k += 8)
      t0[ty + k][tx] = src[(size_t)(r0 + ty + k) * 1024 + c0 + tx];
    __syncthreads();
    if (j < 3) {
      unsigned short* dst = qkvw + (size_t)j * 1024 * 1024;
      float sc = s1[r0 + tx];
#pragma unroll
      for (int k = 0; k < 32; k += 8)
        dst[(size_t)(c0 + ty + k) * 1024 + r0 + tx] = f2bf(t0[tx][ty + k] * sc);
    } else {
#pragma unroll
      for (int k = 0; k < 32; k += 8)
        wft[(size_t)(c0 + ty + k) * 5120 + r0 + tx] = f2bf(t0[tx][ty + k]);
    }
  } else if (bid < 8192) {
    int tile = bid - 4096;
    int c0 = (tile & 31) * 32;
    int r0 = (tile >> 5) * 32;
#pragma unroll
    for (int k = 0; k < 32; k += 8)
      t0[ty + k][tx] = fw[(size_t)(r0 + ty + k) * 1024 + c0 + tx];
    __syncthreads();
#pragma unroll
    for (int k = 0; k < 32; k += 8)
      wft[(size_t)(c0 + ty + k) * 5120 + 1024 + r0 + tx] = f2bf(t0[tx][ty + k]);
  } else {
    int tile = bid - 8192;
    int c0 = (tile & 127) * 32;
    int d0 = (tile >> 7) * 32;
#pragma unroll
    for (int k = 0; k < 32; k += 8) {
      t0[ty + k][tx] = gw[(size_t)(d0 + ty + k) * 4096 + c0 + tx];
      t1[ty + k][tx] = vw[(size_t)(d0 + ty + k) * 4096 + c0 + tx];
    }
    __syncthreads();
    float sc = s2[d0 + tx];
#pragma unroll
    for (int k = 0; k < 32; k += 8) {
      gvt[(size_t)(2 * (c0 + ty + k)) * 1024 + d0 + tx] = f2bf(t0[tx][ty + k] * sc);
      gvt[(size_t)(2 * (c0 + ty + k) + 1) * 1024 + d0 + tx] = f2bf(t1[tx][ty + k] * sc);
    }
  }
}

// activation transpose (V -> V^T) bf16, coalesced via LDS
__global__ __launch_bounds__(256) void transpose_act(
    const unsigned short* __restrict__ in, unsigned short* __restrict__ out,
    int ld_in, int ld_out)
{
  __shared__ float tile[32][33];
  int c0 = blockIdx.x * 32;
  int r0 = blockIdx.y * 32;
  int tx = threadIdx.x;
  int ty = threadIdx.y;
#pragma unroll
  for (int j = 0; j < 32; j += 8)
    tile[ty + j][tx] = b2f(in[(size_t)(r0 + ty + j) * ld_in + c0 + tx]);
  __syncthreads();
#pragma unroll
  for (int j = 0; j < 32; j += 8)
    out[(size_t)(c0 + ty + j) * ld_out + r0 + tx] = f2bf(tile[tx][ty + j]);
}

// embb[v][d] = bf16(embed[v][d] * lnf[d])  (final-LN folded into tied embed)
__global__ __launch_bounds__(256) void convert_embb(
    const float* __restrict__ in, const float* __restrict__ lnf,
    unsigned short* __restrict__ out, size_t n)
{
  size_t i = ((size_t)blockIdx.x * 256 + threadIdx.x) * 4;
  if (i + 3 < n) {
    float4 v = *(const float4*)(in + i);
    int d = (int)(i & 1023);
    out[i] = f2bf(v.x * lnf[d]);
    out[i + 1] = f2bf(v.y * lnf[d + 1]);
    out[i + 2] = f2bf(v.z * lnf[d + 2]);
    out[i + 3] = f2bf(v.w * lnf[d + 3]);
  }
}

extern "C" void kernel_launch(void* const* d_in, const int* in_sizes, int n_in,
                              void* d_out, int out_size, void* d_ws, size_t ws_size,
                              hipStream_t stream)
{
  const int L = L_SEQ, D = DMODEL, F = FFN_F, V = VOCAB;
  const int* ids = (const int*)d_in[0];
  const float* embed = (const float*)d_in[1];
  const float* pos = (const float*)d_in[2];
  const float* wq = (const float*)d_in[3];
  const float* wk = (const float*)d_in[4];
  const float* wv = (const float*)d_in[5];
  const float* wo = (const float*)d_in[6];
  const float* gatew = (const float*)d_in[7];
  const float* valw = (const float*)d_in[8];
  const float* ffow = (const float*)d_in[9];
  const float* ln1 = (const float*)d_in[10];
  const float* ln2 = (const float*)d_in[11];
  const float* lnf = (const float*)d_in[12];

  char* ws = (char*)d_ws;
  size_t off = 0;
  auto alloc = [&](size_t bytes) -> void* {
    void* p = ws + off;
    off += (bytes + 255) & ~(size_t)255;
    return p;
  };
  float* x = (float*)alloc((size_t)L * D * 4);
  float* pbuf = (float*)alloc((size_t)2 * L * D * 4);
  unsigned short* xhat = (unsigned short*)alloc((size_t)L * D * 2);
  unsigned short* qkvb = (unsigned short*)alloc((size_t)L * 3 * D * 2);
  unsigned short* vtb = (unsigned short*)alloc((size_t)L * D * 2);
  unsigned short* ohb = (unsigned short*)alloc((size_t)L * 5120 * 2);
  unsigned short* qkvw = (unsigned short*)alloc((size_t)NLAYER * 3 * D * D * 2);
  unsigned short* gvt = (unsigned short*)alloc((size_t)NLAYER * 2 * F * D * 2);
  unsigned short* wft = (unsigned short*)alloc((size_t)NLAYER * D * 5120 * 2);
  unsigned short* embb = (unsigned short*)alloc((size_t)V * D * 2);

  dim3 blk(256);
  dim3 blk512(512);
  dim3 blkT(32, 8);

  convert_embb<<<(unsigned)((size_t)V * D / 1024), blk, 0, stream>>>(
      embed, lnf, embb, (size_t)V * D);
  prep_weights_all<<<NLAYER * 12288, blkT, 0, stream>>>(
      wq, wk, wv, wo, gatew, valw, ffow, ln1, ln2, qkvw, wft, gvt);

  for (int i = 0; i < NLAYER; i++) {
    unsigned short* qkvw_l = qkvw + (size_t)i * 3 * D * D;
    unsigned short* gvt_l = gvt + (size_t)i * 2 * F * D;
    unsigned short* wft_l = wft + (size_t)i * D * 5120;

    // layer 0: embed-init (mode 2); others: fold residual partials (mode 1)
    rmsnorm_fold<<<L, blk, 0, stream>>>(
        i == 0 ? nullptr : x, pbuf, pbuf + (size_t)L * D,
        ids, embed, pos, xhat, x, i == 0 ? 2 : 1);

    // QKV projection (LN scale folded into qkvw); coalesced [L][3072] output
    gemm_fast<E_BF16><<<dim3(24 * 16), blk, 0, stream>>>(
        xhat, qkvw_l, qkvb, L, 3 * D, D, D, D, 3 * D, 1.0f, 24);

    transpose_act<<<dim3(D / 32, L / 32), blkT, 0, stream>>>(qkvb + 2 * D, vtb, 3 * D, L);

    flash_attn<<<dim3(512), dim3(128), 0, stream>>>(
        qkvb, qkvb + D, vtb, ohb, 3 * D, 5120);

    // swiglu: exactly 256 blocks = 1 full wave
    gemm8p<E_SWIGLU><<<dim3(8 * 32), blk512, 0, stream>>>(
        xhat, gvt_l, ohb + 1024, L, 2 * F, D, D, D, 5120, 1.0f, 8);

    // combined output GEMM: [O | swiglu] * [wo^T ; ffo^T], split-K=2 partials
    gemm_fast<E_PART><<<dim3(8 * 16, 1, 2), blk, 0, stream>>>(
        ohb, wft_l, pbuf, L, D, 5120, 5120, 5120, D, 1.0f, 8);
  }

  rmsnorm_fold<<<L, blk, 0, stream>>>(x, pbuf, pbuf + (size_t)L * D,
                                      ids, embed, pos, xhat, x, 1);
  gemm8p<E_F32><<<dim3(8 * 125), blk512, 0, stream>>>(
      xhat, embb, d_out, L, V, D, D, D, V, 1.0f, 8);
}

// Round 13
// 1178.761 us; speedup vs baseline: 1.0530x; 1.0381x over previous
//
#include <hip/hip_runtime.h>
#include <cstdint>
#include <cstddef>

#define L_SEQ 2048
#define DMODEL 1024
#define NHEAD 16
#define DHEAD 64
#define FFN_F 4096
#define VOCAB 32000
#define NLAYER 4

typedef __attribute__((ext_vector_type(8))) short short8;
typedef __attribute__((ext_vector_type(4))) float f32x4;

__device__ __forceinline__ unsigned short f2bf(float f) {
  unsigned int u = __float_as_uint(f);
  u += 0x7fffu + ((u >> 16) & 1u);
  return (unsigned short)(u >> 16);
}
__device__ __forceinline__ float b2f(unsigned short h) {
  return __uint_as_float(((unsigned int)h) << 16);
}

__device__ __forceinline__ void glds16(const unsigned short* g, unsigned short* l) {
  __builtin_amdgcn_global_load_lds(
      (const __attribute__((address_space(1))) unsigned int*)g,
      (__attribute__((address_space(3))) unsigned int*)l, 16, 0, 0);
}

__device__ __forceinline__ float rmax16(float v) {
  v = fmaxf(v, __shfl_xor(v, 1));
  v = fmaxf(v, __shfl_xor(v, 2));
  v = fmaxf(v, __shfl_xor(v, 4));
  v = fmaxf(v, __shfl_xor(v, 8));
  return v;
}
__device__ __forceinline__ float rsum16(float v) {
  v += __shfl_xor(v, 1);
  v += __shfl_xor(v, 2);
  v += __shfl_xor(v, 4);
  v += __shfl_xor(v, 8);
  return v;
}

#define MFMA(ACC, AF, BF) \
  ACC = __builtin_amdgcn_mfma_f32_16x16x32_bf16(AF, BF, ACC, 0, 0, 0)

enum { E_F32 = 0, E_BF16 = 1, E_SWIGLU = 2, E_PART = 3 };

// ============ 8-phase 256x256 GEMM (T2+T3+T4+T5), 512 thr, BK=64 ============
template <int EPI>
__global__ __launch_bounds__(512, 2) void gemm8p(
    const unsigned short* __restrict__ A, const unsigned short* __restrict__ B,
    void* __restrict__ Cg, int M, int N, int K, int lda, int ldb, int ldc,
    float alpha, int nby)
{
  const int nwg = gridDim.x;
  const int orig = blockIdx.x;
  const int q = nwg >> 3, r = nwg & 7;
  const int xcd = orig & 7, rest = orig >> 3;
  const int wgid = (xcd < r ? xcd * (q + 1) : r * (q + 1) + (xcd - r) * q) + rest;
  const int by = wgid % nby, bx = wgid / nby;
  const int mb = by * 256, nb = bx * 256;

  __shared__ __align__(16) unsigned short As_[2][256 * 64];
  __shared__ __align__(16) unsigned short Bs_[2][256 * 64];

  const int tid = threadIdx.x;
  const int lane = tid & 63;
  const int w = tid >> 6;
  const int wm = (w >> 2) * 128;
  const int wn = (w & 3) * 64;
  const int lr = lane & 15;
  const int lg = lane >> 4;
  const int srow = lane >> 3;
  const int scol = ((lane & 7) ^ srow) * 8;
  const int slot0 = (lg ^ (lr & 7)) * 8;
  const int slot1 = ((4 + lg) ^ (lr & 7)) * 8;

  f32x4 acc[8][4];
#pragma unroll
  for (int i = 0; i < 8; i++)
#pragma unroll
    for (int j = 0; j < 4; j++) acc[i][j] = (f32x4){0.f, 0.f, 0.f, 0.f};

  const unsigned short* Ab = A + (size_t)(mb + srow) * lda + scol;
  const unsigned short* Bb = B + (size_t)(nb + srow) * ldb + scol;

  auto stageA = [&](int t, int R) {
    const int s = t & 1, kb = t << 6;
#pragma unroll
    for (int c = 0; c < 2; c++) {
      int cid = w * 2 + c;
      int rb = ((cid >> 3) << 7) + R * 64 + ((cid & 7) << 3);
      glds16(Ab + (size_t)rb * lda + kb, &As_[s][rb * 64]);
    }
  };
  auto stageB = [&](int t, int R) {
    const int s = t & 1, kb = t << 6;
#pragma unroll
    for (int c = 0; c < 2; c++) {
      int cid = w * 2 + c;
      int rb = ((cid >> 2) << 6) + R * 32 + ((cid & 3) << 3);
      glds16(Bb + (size_t)rb * ldb + kb, &Bs_[s][rb * 64]);
    }
  };

  const int nk = K >> 6;
  stageA(0, 0); stageA(0, 1); stageB(0, 0); stageB(0, 1);
  stageA(1, 0); stageB(1, 0); stageB(1, 1);
  asm volatile("s_waitcnt vmcnt(6)" ::: "memory");
  __builtin_amdgcn_s_barrier();

  short8 a[4][2], b0[2][2], b1[2][2];
#pragma unroll
  for (int j = 0; j < 2; j++) {
    b0[j][0] = *(const short8*)&Bs_[0][(wn + j * 16 + lr) * 64 + slot0];
    b0[j][1] = *(const short8*)&Bs_[0][(wn + j * 16 + lr) * 64 + slot1];
  }

  for (int t = 0; t < nk; ++t) {
    const int s = t & 1;
    const unsigned short* Asb = &As_[s][0];
    const unsigned short* Bsb = &Bs_[s][0];

    // phase 1: read A-low; stage A-R2(t+1); MFMA (m-lo x n-lo)
#pragma unroll
    for (int i = 0; i < 4; i++) {
      a[i][0] = *(const short8*)&Asb[(wm + i * 16 + lr) * 64 + slot0];
      a[i][1] = *(const short8*)&Asb[(wm + i * 16 + lr) * 64 + slot1];
    }
    if (t + 1 < nk) stageA(t + 1, 1);
    __builtin_amdgcn_s_barrier();
    __builtin_amdgcn_s_setprio(1);
#pragma unroll
    for (int kk = 0; kk < 2; kk++)
#pragma unroll
      for (int i = 0; i < 4; i++)
#pragma unroll
        for (int j = 0; j < 2; j++) MFMA(acc[i][j], a[i][kk], b0[j][kk]);
    __builtin_amdgcn_s_setprio(0);
    __builtin_amdgcn_s_barrier();

    // phase 2: read B-high; stage A-R1(t+2); MFMA (m-lo x n-hi)
#pragma unroll
    for (int j = 0; j < 2; j++) {
      b1[j][0] = *(const short8*)&Bsb[(wn + 32 + j * 16 + lr) * 64 + slot0];
      b1[j][1] = *(const short8*)&Bsb[(wn + 32 + j * 16 + lr) * 64 + slot1];
    }
    if (t + 2 < nk) stageA(t + 2, 0);
    __builtin_amdgcn_s_barrier();
    __builtin_amdgcn_s_setprio(1);
#pragma unroll
    for (int kk = 0; kk < 2; kk++)
#pragma unroll
      for (int i = 0; i < 4; i++)
#pragma unroll
        for (int j = 0; j < 2; j++) MFMA(acc[i][2 + j], a[i][kk], b1[j][kk]);
    __builtin_amdgcn_s_setprio(0);
    __builtin_amdgcn_s_barrier();

    // phase 3: read A-high; stage B-R1(t+2); MFMA (m-hi x n-hi)
#pragma unroll
    for (int i = 0; i < 4; i++) {
      a[i][0] = *(const short8*)&Asb[(wm + 64 + i * 16 + lr) * 64 + slot0];
      a[i][1] = *(const short8*)&Asb[(wm + 64 + i * 16 + lr) * 64 + slot1];
    }
    if (t + 2 < nk) stageB(t + 2, 0);
    __builtin_amdgcn_s_barrier();
    __builtin_amdgcn_s_setprio(1);
#pragma unroll
    for (int kk = 0; kk < 2; kk++)
#pragma unroll
      for (int i = 0; i < 4; i++)
#pragma unroll
        for (int j = 0; j < 2; j++) MFMA(acc[4 + i][2 + j], a[i][kk], b1[j][kk]);
    __builtin_amdgcn_s_setprio(0);
    __builtin_amdgcn_s_barrier();

    // phase 4: stage B-R2(t+2); MFMA (m-hi x n-lo); counted vmcnt; tail b0 read
    if (t + 2 < nk) stageB(t + 2, 1);
    __builtin_amdgcn_s_barrier();
    __builtin_amdgcn_s_setprio(1);
#pragma unroll
    for (int kk = 0; kk < 2; kk++)
#pragma unroll
      for (int i = 0; i < 4; i++)
#pragma unroll
        for (int j = 0; j < 2; j++) MFMA(acc[4 + i][j], a[i][kk], b0[j][kk]);
    __builtin_amdgcn_s_setprio(0);
    if (t + 2 < nk) {
      asm volatile("s_waitcnt vmcnt(6)" ::: "memory");
    } else {
      asm volatile("s_waitcnt vmcnt(0)" ::: "memory");
    }
    __builtin_amdgcn_s_barrier();
    if (t + 1 < nk) {
      const unsigned short* Bn = &Bs_[s ^ 1][0];
#pragma unroll
      for (int j = 0; j < 2; j++) {
        b0[j][0] = *(const short8*)&Bn[(wn + j * 16 + lr) * 64 + slot0];
        b0[j][1] = *(const short8*)&Bn[(wn + j * 16 + lr) * 64 + slot1];
      }
    }
  }

#pragma unroll
  for (int i = 0; i < 8; i++) {
#pragma unroll
    for (int j = 0; j < 4; j++) {
      int oc = nb + wn + 16 * j + lr;
#pragma unroll
      for (int r4 = 0; r4 < 4; r4++) {
        int orow = mb + wm + 16 * i + lg * 4 + r4;
        float v = acc[i][j][r4] * alpha;
        if (EPI == E_F32) {
          ((float*)Cg)[(size_t)orow * ldc + oc] = v;
        } else if (EPI == E_BF16) {
          ((unsigned short*)Cg)[(size_t)orow * ldc + oc] = f2bf(v);
        } else if (EPI == E_SWIGLU) {
          float other = __shfl_xor(v, 1);
          float g = (lane & 1) ? other : v;
          float vv = (lane & 1) ? v : other;
          float sw = g / (1.0f + expf(-g)) * vv;
          if (!(lane & 1))
            ((unsigned short*)Cg)[(size_t)orow * ldc + (oc >> 1)] = f2bf(sw);
        }
      }
    }
  }
}

// ============ 128x128 2-phase GEMM ==========================================
template <int EPI>
__global__ __launch_bounds__(256) void gemm_fast(
    const unsigned short* __restrict__ A, const unsigned short* __restrict__ B,
    void* __restrict__ Cg, int M, int N, int K, int lda, int ldb, int ldc,
    float alpha, int nbx)
{
  const int nwg = gridDim.x;
  const int orig = blockIdx.x;
  const int q = nwg >> 3, r = nwg & 7;
  const int xcd = orig & 7, rest = orig >> 3;
  const int wgid = (xcd < r ? xcd * (q + 1) : r * (q + 1) + (xcd - r) * q) + rest;
  const int bx = wgid % nbx, by = wgid / nbx;
  const int mb = by * 128;
  const int nb = bx * 128;

  const int Keff = (EPI == E_PART) ? (K >> 1) : K;
  const int koff = (EPI == E_PART) ? blockIdx.z * Keff : 0;

  __shared__ __align__(16) unsigned short As[2][128 * 64];
  __shared__ __align__(16) unsigned short Bs[2][128 * 64];

  const int tid = threadIdx.x;
  const int lane = tid & 63;
  const int wave = tid >> 6;
  const int wm = (wave >> 1) * 64;
  const int wn = (wave & 1) * 64;
  const int lr = lane & 15;
  const int lg = lane >> 4;

  const int srow = lane >> 3;
  const int scol = ((lane & 7) ^ srow) * 8;

  f32x4 acc[4][4];
#pragma unroll
  for (int i = 0; i < 4; i++)
#pragma unroll
    for (int j = 0; j < 4; j++) acc[i][j] = (f32x4){0.f, 0.f, 0.f, 0.f};

  const unsigned short* Abase = A + (size_t)(mb + wave * 32 + srow) * lda + koff + scol;
  const unsigned short* Bbase = B + (size_t)(nb + wave * 32 + srow) * ldb + koff + scol;

  auto stage = [&](int kb, int b) {
#pragma unroll
    for (int c = 0; c < 4; c++)
      glds16(Abase + (size_t)(c * 8) * lda + kb, &As[b][(wave * 32 + c * 8) * 64]);
#pragma unroll
    for (int c = 0; c < 4; c++)
      glds16(Bbase + (size_t)(c * 8) * ldb + kb, &Bs[b][(wave * 32 + c * 8) * 64]);
  };

  stage(0, 0);
  __syncthreads();
  int cur = 0;
  const int nk = Keff >> 6;

  for (int t = 0; t < nk; ++t) {
    if (t + 1 < nk) stage((t + 1) << 6, cur ^ 1);

    short8 af[2][4], bfb[2][4];
#pragma unroll
    for (int h = 0; h < 2; h++) {
      const int swz = ((h * 4 + lg) ^ (lr & 7)) * 8;
#pragma unroll
      for (int i = 0; i < 4; i++) {
        af[h][i] = *(const short8*)&As[cur][(wm + 16 * i + lr) * 64 + swz];
        bfb[h][i] = *(const short8*)&Bs[cur][(wn + 16 * i + lr) * 64 + swz];
      }
    }
#pragma unroll
    for (int h = 0; h < 2; h++)
#pragma unroll
      for (int i = 0; i < 4; i++)
#pragma unroll
        for (int j = 0; j < 4; j++) MFMA(acc[i][j], af[h][i], bfb[h][j]);

    __syncthreads();
    cur ^= 1;
  }

#pragma unroll
  for (int i = 0; i < 4; i++) {
#pragma unroll
    for (int j = 0; j < 4; j++) {
      int oc = nb + wn + 16 * j + lr;
#pragma unroll
      for (int r4 = 0; r4 < 4; r4++) {
        int orow = mb + wm + 16 * i + lg * 4 + r4;
        float v = acc[i][j][r4] * alpha;
        if (EPI == E_F32) {
          ((float*)Cg)[(size_t)orow * ldc + oc] = v;
        } else if (EPI == E_BF16) {
          ((unsigned short*)Cg)[(size_t)orow * ldc + oc] = f2bf(v);
        } else {  // E_PART
          float* C = (float*)Cg + (size_t)blockIdx.z * ((size_t)L_SEQ * DMODEL);
          C[(size_t)orow * ldc + oc] = v;
        }
      }
    }
  }
}

// ---------------- fused flash attention (balanced, QBLK=64, 2 waves) --------
__global__ __launch_bounds__(128) void flash_attn(
    const unsigned short* __restrict__ Qg, const unsigned short* __restrict__ Kg,
    const unsigned short* __restrict__ Vt, unsigned short* __restrict__ Og,
    int ldq, int ldo)
{
  const int bid = blockIdx.x;
  const int slot = bid & 255, ph = bid >> 8;
  const int h = slot >> 4;
  const int qs = slot & 15;
  const int qb = ph ? (31 - qs) : qs;

  const int tid = threadIdx.x;
  const int lane = tid & 63;
  const int w = tid >> 6;
  const int lr = lane & 15;
  const int lg = lane >> 4;

  __shared__ __align__(16) unsigned short KsL[2][64 * 64];
  __shared__ __align__(16) unsigned short VsL[2][64 * 64];
  __shared__ __align__(16) unsigned short Ps[2][32 * 64];

  const int srow = lane >> 3;
  const int scol = ((lane & 7) ^ srow) * 8;

  short8 qf[2][2];
#pragma unroll
  for (int i = 0; i < 2; i++)
#pragma unroll
    for (int kk = 0; kk < 2; kk++)
      qf[i][kk] = *(const short8*)(Qg +
          (size_t)(qb * 64 + w * 32 + i * 16 + lr) * ldq + h * 64 + kk * 32 + lg * 8);

  f32x4 acc_o[2][4];
  float m_st[2][4], l_st[2][4];
#pragma unroll
  for (int i = 0; i < 2; i++)
#pragma unroll
    for (int j = 0; j < 4; j++) acc_o[i][j] = (f32x4){0.f, 0.f, 0.f, 0.f};
#pragma unroll
  for (int i = 0; i < 2; i++)
#pragma unroll
    for (int r = 0; r < 4; r++) { m_st[i][r] = -1e30f; l_st[i][r] = 0.f; }

  const int ntiles = qb + 1;
  const int qmin = qb * 64 + w * 32;

  auto stage = [&](int t, int buf) {
#pragma unroll
    for (int c = 0; c < 4; c++) {
      int row = w * 32 + c * 8 + srow;
      glds16(Kg + (size_t)(t * 64 + row) * ldq + h * 64 + scol,
             &KsL[buf][row * 64]);
      glds16(Vt + (size_t)(h * 64 + row) * L_SEQ + t * 64 + scol,
             &VsL[buf][row * 64]);
    }
  };

  stage(0, 0);
  __syncthreads();
  int buf = 0;

  for (int t = 0; t < ntiles; t++) {
    if (t + 1 < ntiles) stage(t + 1, buf ^ 1);

    f32x4 sa[2][4];
#pragma unroll
    for (int i = 0; i < 2; i++)
#pragma unroll
      for (int j = 0; j < 4; j++) sa[i][j] = (f32x4){0.f, 0.f, 0.f, 0.f};
#pragma unroll
    for (int kk = 0; kk < 2; kk++) {
      short8 kf[4];
#pragma unroll
      for (int j = 0; j < 4; j++)
        kf[j] = *(const short8*)&KsL[buf][(j * 16 + lr) * 64 + ((kk * 4 + lg) ^ (lr & 7)) * 8];
#pragma unroll
      for (int i = 0; i < 2; i++)
#pragma unroll
        for (int j = 0; j < 4; j++) MFMA(sa[i][j], qf[i][kk], kf[j]);
    }

    const bool diag = (t * 64 + 63) > qmin;
#pragma unroll
    for (int i = 0; i < 2; i++)
#pragma unroll
      for (int j = 0; j < 4; j++)
#pragma unroll
        for (int r = 0; r < 4; r++) {
          float s = sa[i][j][r] * 0.125f;
          if (diag) {
            int kg = t * 64 + j * 16 + lr;
            int qg = qmin + i * 16 + lg * 4 + r;
            if (kg > qg) s = -1e30f;
          }
          sa[i][j][r] = s;
        }

    float fsc[2][4], mnew[2][4];
#pragma unroll
    for (int i = 0; i < 2; i++)
#pragma unroll
      for (int r = 0; r < 4; r++) {
        float mx = fmaxf(fmaxf(sa[i][0][r], sa[i][1][r]), fmaxf(sa[i][2][r], sa[i][3][r]));
        mx = rmax16(mx);
        float mn = fmaxf(m_st[i][r], mx);
        mnew[i][r] = mn;
        fsc[i][r] = __expf(m_st[i][r] - mn);
        m_st[i][r] = mn;
      }
#pragma unroll
    for (int i = 0; i < 2; i++)
#pragma unroll
      for (int r = 0; r < 4; r++) {
        float ls = 0.f;
#pragma unroll
        for (int j = 0; j < 4; j++) {
          float p = __expf(sa[i][j][r] - mnew[i][r]);
          sa[i][j][r] = p;
          ls += p;
        }
        ls = rsum16(ls);
        l_st[i][r] = l_st[i][r] * fsc[i][r] + ls;
      }
#pragma unroll
    for (int i = 0; i < 2; i++)
#pragma unroll
      for (int j = 0; j < 4; j++)
#pragma unroll
        for (int r = 0; r < 4; r++) acc_o[i][j][r] *= fsc[i][r];

#pragma unroll
    for (int i = 0; i < 2; i++)
#pragma unroll
      for (int j = 0; j < 4; j++)
#pragma unroll
        for (int r = 0; r < 4; r++) {
          int qrl = lg * 4 + r;
          int idx = (i * 16 + qrl) * 64 + (((j * 2 + (lr >> 3)) ^ (qrl & 7)) * 8) + (lr & 7);
          Ps[w][idx] = f2bf(sa[i][j][r]);
        }

#pragma unroll
    for (int kk = 0; kk < 2; kk++) {
      short8 pf[2], vf[4];
#pragma unroll
      for (int i = 0; i < 2; i++)
        pf[i] = *(const short8*)&Ps[w][(i * 16 + lr) * 64 + ((kk * 4 + lg) ^ (lr & 7)) * 8];
#pragma unroll
      for (int j = 0; j < 4; j++)
        vf[j] = *(const short8*)&VsL[buf][(j * 16 + lr) * 64 + ((kk * 4 + lg) ^ (lr & 7)) * 8];
#pragma unroll
      for (int i = 0; i < 2; i++)
#pragma unroll
        for (int j = 0; j < 4; j++) MFMA(acc_o[i][j], pf[i], vf[j]);
    }

    __syncthreads();
    buf ^= 1;
  }

  float inv[2][4];
#pragma unroll
  for (int i = 0; i < 2; i++)
#pragma unroll
    for (int r = 0; r < 4; r++) inv[i][r] = 1.0f / l_st[i][r];
#pragma unroll
  for (int i = 0; i < 2; i++)
#pragma unroll
    for (int j = 0; j < 4; j++)
#pragma unroll
      for (int r = 0; r < 4; r++) {
        size_t row = qmin + i * 16 + lg * 4 + r;
        Og[row * ldo + h * 64 + j * 16 + lr] = f2bf(acc_o[i][j][r] * inv[i][r]);
      }
}

// rmsnorm with residual fold: xnew = x + p1 + p2 (if fold); o1 = bf16(xnew*inv)
__global__ __launch_bounds__(256) void rmsnorm_fold(
    const float* __restrict__ xin,
    const float* __restrict__ p1, const float* __restrict__ p2,
    unsigned short* __restrict__ o1, float* __restrict__ xout, int fold)
{
  int row = blockIdx.x;
  int tid = threadIdx.x;
  float v[4];
  float ss = 0.f;
#pragma unroll
  for (int i = 0; i < 4; i++) {
    size_t idx = (size_t)row * DMODEL + tid + 256 * i;
    float val = xin[idx];
    if (fold) {
      val += p1[idx] + p2[idx];
      xout[idx] = val;
    }
    v[i] = val;
    ss += val * val;
  }
#pragma unroll
  for (int o = 32; o > 0; o >>= 1) ss += __shfl_xor(ss, o);
  __shared__ float red[4];
  if ((tid & 63) == 0) red[tid >> 6] = ss;
  __syncthreads();
  ss = red[0] + red[1] + red[2] + red[3];
  float inv = rsqrtf(ss / DMODEL + 1e-6f);
#pragma unroll
  for (int i = 0; i < 4; i++) {
    size_t idx = (size_t)row * DMODEL + tid + 256 * i;
    o1[idx] = f2bf(v[i] * inv);
  }
}

// one launch: all weight prep for a layer; LN scales folded into weights
__global__ __launch_bounds__(256) void prep_weights(
    const float* __restrict__ wq, const float* __restrict__ wk,
    const float* __restrict__ wv, const float* __restrict__ wo,
    const float* __restrict__ gw, const float* __restrict__ vw,
    const float* __restrict__ fw, const float* __restrict__ s1,
    const float* __restrict__ s2,
    unsigned short* __restrict__ qkvw, unsigned short* __restrict__ wft,
    unsigned short* __restrict__ gvt)
{
  __shared__ float t0[32][33], t1[32][33];
  int bid = blockIdx.x;
  int tx = threadIdx.x, ty = threadIdx.y;
  if (bid < 4096) {
    int j = bid >> 10, tile = bid & 1023;
    int c0 = (tile & 31) * 32, r0 = (tile >> 5) * 32;
    const float* src = j == 0 ? wq : j == 1 ? wk : j == 2 ? wv : wo;
#pragma unroll
    for (int k = 0; k < 32; k += 8)
      t0[ty + k][tx] = src[(size_t)(r0 + ty + k) * 1024 + c0 + tx];
    __syncthreads();
    if (j < 3) {
      unsigned short* dst = qkvw + (size_t)j * 1024 * 1024;
      float sc = s1[r0 + tx];
#pragma unroll
      for (int k = 0; k < 32; k += 8)
        dst[(size_t)(c0 + ty + k) * 1024 + r0 + tx] = f2bf(t0[tx][ty + k] * sc);
    } else {
#pragma unroll
      for (int k = 0; k < 32; k += 8)
        wft[(size_t)(c0 + ty + k) * 5120 + r0 + tx] = f2bf(t0[tx][ty + k]);
    }
  } else if (bid < 8192) {
    int tile = bid - 4096;
    int c0 = (tile & 31) * 32;
    int r0 = (tile >> 5) * 32;
#pragma unroll
    for (int k = 0; k < 32; k += 8)
      t0[ty + k][tx] = fw[(size_t)(r0 + ty + k) * 1024 + c0 + tx];
    __syncthreads();
#pragma unroll
    for (int k = 0; k < 32; k += 8)
      wft[(size_t)(c0 + ty + k) * 5120 + 1024 + r0 + tx] = f2bf(t0[tx][ty + k]);
  } else {
    int tile = bid - 8192;
    int c0 = (tile & 127) * 32;
    int d0 = (tile >> 7) * 32;
#pragma unroll
    for (int k = 0; k < 32; k += 8) {
      t0[ty + k][tx] = gw[(size_t)(d0 + ty + k) * 4096 + c0 + tx];
      t1[ty + k][tx] = vw[(size_t)(d0 + ty + k) * 4096 + c0 + tx];
    }
    __syncthreads();
    float sc = s2[d0 + tx];
#pragma unroll
    for (int k = 0; k < 32; k += 8) {
      gvt[(size_t)(2 * (c0 + ty + k)) * 1024 + d0 + tx] = f2bf(t0[tx][ty + k] * sc);
      gvt[(size_t)(2 * (c0 + ty + k) + 1) * 1024 + d0 + tx] = f2bf(t1[tx][ty + k] * sc);
    }
  }
}

// activation transpose (V -> V^T) bf16
__global__ __launch_bounds__(256) void transpose_act(
    const unsigned short* __restrict__ in, unsigned short* __restrict__ out,
    int ld_in, int ld_out)
{
  __shared__ float tile[32][33];
  int c0 = blockIdx.x * 32;
  int r0 = blockIdx.y * 32;
  int tx = threadIdx.x;
  int ty = threadIdx.y;
#pragma unroll
  for (int j = 0; j < 32; j += 8)
    tile[ty + j][tx] = b2f(in[(size_t)(r0 + ty + j) * ld_in + c0 + tx]);
  __syncthreads();
#pragma unroll
  for (int j = 0; j < 32; j += 8)
    out[(size_t)(c0 + ty + j) * ld_out + r0 + tx] = f2bf(tile[tx][ty + j]);
}

// embb[v][d] = bf16(embed[v][d] * lnf[d])  (final-LN folded into tied embed)
__global__ __launch_bounds__(256) void convert_embb(
    const float* __restrict__ in, const float* __restrict__ lnf,
    unsigned short* __restrict__ out, size_t n)
{
  size_t i = ((size_t)blockIdx.x * 256 + threadIdx.x) * 4;
  if (i + 3 < n) {
    float4 v = *(const float4*)(in + i);
    int d = (int)(i & 1023);
    out[i] = f2bf(v.x * lnf[d]);
    out[i + 1] = f2bf(v.y * lnf[d + 1]);
    out[i + 2] = f2bf(v.z * lnf[d + 2]);
    out[i + 3] = f2bf(v.w * lnf[d + 3]);
  }
}

__global__ __launch_bounds__(256) void embed_kernel(
    const int* __restrict__ ids, const float* __restrict__ emb,
    const float* __restrict__ pos, float* __restrict__ x)
{
  int l = blockIdx.x;
  int id = ids[l];
#pragma unroll
  for (int i = 0; i < 4; i++) {
    int d = threadIdx.x + 256 * i;
    x[(size_t)l * DMODEL + d] = emb[(size_t)id * DMODEL + d] + pos[(size_t)l * DMODEL + d];
  }
}

extern "C" void kernel_launch(void* const* d_in, const int* in_sizes, int n_in,
                              void* d_out, int out_size, void* d_ws, size_t ws_size,
                              hipStream_t stream)
{
  const int L = L_SEQ, D = DMODEL, F = FFN_F, V = VOCAB;
  const int* ids = (const int*)d_in[0];
  const float* embed = (const float*)d_in[1];
  const float* pos = (const float*)d_in[2];
  const float* wq = (const float*)d_in[3];
  const float* wk = (const float*)d_in[4];
  const float* wv = (const float*)d_in[5];
  const float* wo = (const float*)d_in[6];
  const float* gatew = (const float*)d_in[7];
  const float* valw = (const float*)d_in[8];
  const float* ffow = (const float*)d_in[9];
  const float* ln1 = (const float*)d_in[10];
  const float* ln2 = (const float*)d_in[11];
  const float* lnf = (const float*)d_in[12];

  char* ws = (char*)d_ws;
  size_t off = 0;
  auto alloc = [&](size_t bytes) -> void* {
    void* p = ws + off;
    off += (bytes + 255) & ~(size_t)255;
    return p;
  };
  float* x = (float*)alloc((size_t)L * D * 4);
  float* pbuf = (float*)alloc((size_t)2 * L * D * 4);
  unsigned short* xhat = (unsigned short*)alloc((size_t)L * D * 2);
  unsigned short* qkvb = (unsigned short*)alloc((size_t)L * 3 * D * 2);
  unsigned short* vtb = (unsigned short*)alloc((size_t)L * D * 2);
  unsigned short* ohb = (unsigned short*)alloc((size_t)L * 5120 * 2);
  unsigned short* qkvw = (unsigned short*)alloc((size_t)3 * D * D * 2);
  unsigned short* gvt = (unsigned short*)alloc((size_t)2 * F * D * 2);
  unsigned short* wft = (unsigned short*)alloc((size_t)D * 5120 * 2);
  unsigned short* embb = (unsigned short*)alloc((size_t)V * D * 2);

  dim3 blk(256);
  dim3 blk512(512);
  dim3 blkT(32, 8);

  embed_kernel<<<L, blk, 0, stream>>>(ids, embed, pos, x);
  convert_embb<<<(unsigned)((size_t)V * D / 1024), blk, 0, stream>>>(
      embed, lnf, embb, (size_t)V * D);

  for (int i = 0; i < NLAYER; i++) {
    prep_weights<<<12288, blkT, 0, stream>>>(
        wq + (size_t)i * D * D, wk + (size_t)i * D * D, wv + (size_t)i * D * D,
        wo + (size_t)i * D * D, gatew + (size_t)i * D * F, valw + (size_t)i * D * F,
        ffow + (size_t)i * F * D, ln1 + (size_t)i * D, ln2 + (size_t)i * D,
        qkvw, wft, gvt);

    rmsnorm_fold<<<L, blk, 0, stream>>>(x, pbuf, pbuf + (size_t)L * D,
                                        xhat, x, i > 0 ? 1 : 0);

    // QKV projection (LN scale folded into qkvw); fully-resident 384 blocks
    gemm_fast<E_BF16><<<dim3(24 * 16), blk, 0, stream>>>(
        xhat, qkvw, qkvb, L, 3 * D, D, D, D, 3 * D, 1.0f, 24);

    transpose_act<<<dim3(D / 32, L / 32), blkT, 0, stream>>>(qkvb + 2 * D, vtb, 3 * D, L);

    flash_attn<<<dim3(512), dim3(128), 0, stream>>>(qkvb, qkvb + D, vtb, ohb, 3 * D, 5120);

    // swiglu (LN scale folded into gvt): exactly 256 blocks = 1 full wave
    gemm8p<E_SWIGLU><<<dim3(8 * 32), blk512, 0, stream>>>(
        xhat, gvt, ohb + 1024, L, 2 * F, D, D, D, 5120, 1.0f, 8);

    // combined output GEMM: [O | swiglu] * [wo^T ; ffo^T], split-K=2 partials
    gemm_fast<E_PART><<<dim3(8 * 16, 1, 2), blk, 0, stream>>>(
        ohb, wft, pbuf, L, D, 5120, 5120, 5120, D, 1.0f, 8);
  }

  rmsnorm_fold<<<L, blk, 0, stream>>>(x, pbuf, pbuf + (size_t)L * D,
                                      xhat, x, 1);
  gemm8p<E_F32><<<dim3(8 * 125), blk512, 0, stream>>>(
      xhat, embb, d_out, L, V, D, D, D, V, 1.0f, 8);
}

// Round 14
// 1114.255 us; speedup vs baseline: 1.1139x; 1.0579x over previous
//
#include <hip/hip_runtime.h>
#include <cstdint>
#include <cstddef>

#define L_SEQ 2048
#define DMODEL 1024
#define NHEAD 16
#define DHEAD 64
#define FFN_F 4096
#define VOCAB 32000
#define NLAYER 4

typedef __attribute__((ext_vector_type(8))) short short8;
typedef __attribute__((ext_vector_type(4))) float f32x4;

__device__ __forceinline__ unsigned short f2bf(float f) {
  unsigned int u = __float_as_uint(f);
  u += 0x7fffu + ((u >> 16) & 1u);
  return (unsigned short)(u >> 16);
}
__device__ __forceinline__ float b2f(unsigned short h) {
  return __uint_as_float(((unsigned int)h) << 16);
}

__device__ __forceinline__ void glds16(const unsigned short* g, unsigned short* l) {
  __builtin_amdgcn_global_load_lds(
      (const __attribute__((address_space(1))) unsigned int*)g,
      (__attribute__((address_space(3))) unsigned int*)l, 16, 0, 0);
}

__device__ __forceinline__ float rmax16(float v) {
  v = fmaxf(v, __shfl_xor(v, 1));
  v = fmaxf(v, __shfl_xor(v, 2));
  v = fmaxf(v, __shfl_xor(v, 4));
  v = fmaxf(v, __shfl_xor(v, 8));
  return v;
}
__device__ __forceinline__ float rsum16(float v) {
  v += __shfl_xor(v, 1);
  v += __shfl_xor(v, 2);
  v += __shfl_xor(v, 4);
  v += __shfl_xor(v, 8);
  return v;
}

#define MFMA(ACC, AF, BF) \
  ACC = __builtin_amdgcn_mfma_f32_16x16x32_bf16(AF, BF, ACC, 0, 0, 0)

enum { E_F32 = 0, E_BF16 = 1, E_SWIGLU = 2, E_PART = 3 };

// ============ 8-phase 256x256 GEMM (T2+T3+T4+T5), 512 thr, BK=64 ============
template <int EPI>
__global__ __launch_bounds__(512, 2) void gemm8p(
    const unsigned short* __restrict__ A, const unsigned short* __restrict__ B,
    void* __restrict__ Cg, int M, int N, int K, int lda, int ldb, int ldc,
    float alpha, int nby)
{
  const int nwg = gridDim.x;
  const int orig = blockIdx.x;
  const int q = nwg >> 3, r = nwg & 7;
  const int xcd = orig & 7, rest = orig >> 3;
  const int wgid = (xcd < r ? xcd * (q + 1) : r * (q + 1) + (xcd - r) * q) + rest;
  const int by = wgid % nby, bx = wgid / nby;
  const int mb = by * 256, nb = bx * 256;

  __shared__ __align__(16) unsigned short As_[2][256 * 64];
  __shared__ __align__(16) unsigned short Bs_[2][256 * 64];

  const int tid = threadIdx.x;
  const int lane = tid & 63;
  const int w = tid >> 6;
  const int wm = (w >> 2) * 128;
  const int wn = (w & 3) * 64;
  const int lr = lane & 15;
  const int lg = lane >> 4;
  const int srow = lane >> 3;
  const int scol = ((lane & 7) ^ srow) * 8;
  const int slot0 = (lg ^ (lr & 7)) * 8;
  const int slot1 = ((4 + lg) ^ (lr & 7)) * 8;

  f32x4 acc[8][4];
#pragma unroll
  for (int i = 0; i < 8; i++)
#pragma unroll
    for (int j = 0; j < 4; j++) acc[i][j] = (f32x4){0.f, 0.f, 0.f, 0.f};

  const unsigned short* Ab = A + (size_t)(mb + srow) * lda + scol;
  const unsigned short* Bb = B + (size_t)(nb + srow) * ldb + scol;

  auto stageA = [&](int t, int R) {
    const int s = t & 1, kb = t << 6;
#pragma unroll
    for (int c = 0; c < 2; c++) {
      int cid = w * 2 + c;
      int rb = ((cid >> 3) << 7) + R * 64 + ((cid & 7) << 3);
      glds16(Ab + (size_t)rb * lda + kb, &As_[s][rb * 64]);
    }
  };
  auto stageB = [&](int t, int R) {
    const int s = t & 1, kb = t << 6;
#pragma unroll
    for (int c = 0; c < 2; c++) {
      int cid = w * 2 + c;
      int rb = ((cid >> 2) << 6) + R * 32 + ((cid & 3) << 3);
      glds16(Bb + (size_t)rb * ldb + kb, &Bs_[s][rb * 64]);
    }
  };

  const int nk = K >> 6;
  stageA(0, 0); stageA(0, 1); stageB(0, 0); stageB(0, 1);
  stageA(1, 0); stageB(1, 0); stageB(1, 1);
  asm volatile("s_waitcnt vmcnt(6)" ::: "memory");
  __builtin_amdgcn_s_barrier();

  short8 a[4][2], b0[2][2], b1[2][2];
#pragma unroll
  for (int j = 0; j < 2; j++) {
    b0[j][0] = *(const short8*)&Bs_[0][(wn + j * 16 + lr) * 64 + slot0];
    b0[j][1] = *(const short8*)&Bs_[0][(wn + j * 16 + lr) * 64 + slot1];
  }

  for (int t = 0; t < nk; ++t) {
    const int s = t & 1;
    const unsigned short* Asb = &As_[s][0];
    const unsigned short* Bsb = &Bs_[s][0];

    // phase 1: read A-low; stage A-R2(t+1); MFMA (m-lo x n-lo)
#pragma unroll
    for (int i = 0; i < 4; i++) {
      a[i][0] = *(const short8*)&Asb[(wm + i * 16 + lr) * 64 + slot0];
      a[i][1] = *(const short8*)&Asb[(wm + i * 16 + lr) * 64 + slot1];
    }
    if (t + 1 < nk) stageA(t + 1, 1);
    __builtin_amdgcn_s_barrier();
    __builtin_amdgcn_s_setprio(1);
#pragma unroll
    for (int kk = 0; kk < 2; kk++)
#pragma unroll
      for (int i = 0; i < 4; i++)
#pragma unroll
        for (int j = 0; j < 2; j++) MFMA(acc[i][j], a[i][kk], b0[j][kk]);
    __builtin_amdgcn_s_setprio(0);
    __builtin_amdgcn_s_barrier();

    // phase 2: read B-high; stage A-R1(t+2); MFMA (m-lo x n-hi)
#pragma unroll
    for (int j = 0; j < 2; j++) {
      b1[j][0] = *(const short8*)&Bsb[(wn + 32 + j * 16 + lr) * 64 + slot0];
      b1[j][1] = *(const short8*)&Bsb[(wn + 32 + j * 16 + lr) * 64 + slot1];
    }
    if (t + 2 < nk) stageA(t + 2, 0);
    __builtin_amdgcn_s_barrier();
    __builtin_amdgcn_s_setprio(1);
#pragma unroll
    for (int kk = 0; kk < 2; kk++)
#pragma unroll
      for (int i = 0; i < 4; i++)
#pragma unroll
        for (int j = 0; j < 2; j++) MFMA(acc[i][2 + j], a[i][kk], b1[j][kk]);
    __builtin_amdgcn_s_setprio(0);
    __builtin_amdgcn_s_barrier();

    // phase 3: read A-high; stage B-R1(t+2); MFMA (m-hi x n-hi)
#pragma unroll
    for (int i = 0; i < 4; i++) {
      a[i][0] = *(const short8*)&Asb[(wm + 64 + i * 16 + lr) * 64 + slot0];
      a[i][1] = *(const short8*)&Asb[(wm + 64 + i * 16 + lr) * 64 + slot1];
    }
    if (t + 2 < nk) stageB(t + 2, 0);
    __builtin_amdgcn_s_barrier();
    __builtin_amdgcn_s_setprio(1);
#pragma unroll
    for (int kk = 0; kk < 2; kk++)
#pragma unroll
      for (int i = 0; i < 4; i++)
#pragma unroll
        for (int j = 0; j < 2; j++) MFMA(acc[4 + i][2 + j], a[i][kk], b1[j][kk]);
    __builtin_amdgcn_s_setprio(0);
    __builtin_amdgcn_s_barrier();

    // phase 4: stage B-R2(t+2); MFMA (m-hi x n-lo); counted vmcnt; tail b0 read
    if (t + 2 < nk) stageB(t + 2, 1);
    __builtin_amdgcn_s_barrier();
    __builtin_amdgcn_s_setprio(1);
#pragma unroll
    for (int kk = 0; kk < 2; kk++)
#pragma unroll
      for (int i = 0; i < 4; i++)
#pragma unroll
        for (int j = 0; j < 2; j++) MFMA(acc[4 + i][j], a[i][kk], b0[j][kk]);
    __builtin_amdgcn_s_setprio(0);
    if (t + 2 < nk) {
      asm volatile("s_waitcnt vmcnt(6)" ::: "memory");
    } else {
      asm volatile("s_waitcnt vmcnt(0)" ::: "memory");
    }
    __builtin_amdgcn_s_barrier();
    if (t + 1 < nk) {
      const unsigned short* Bn = &Bs_[s ^ 1][0];
#pragma unroll
      for (int j = 0; j < 2; j++) {
        b0[j][0] = *(const short8*)&Bn[(wn + j * 16 + lr) * 64 + slot0];
        b0[j][1] = *(const short8*)&Bn[(wn + j * 16 + lr) * 64 + slot1];
      }
    }
  }

#pragma unroll
  for (int i = 0; i < 8; i++) {
#pragma unroll
    for (int j = 0; j < 4; j++) {
      int oc = nb + wn + 16 * j + lr;
#pragma unroll
      for (int r4 = 0; r4 < 4; r4++) {
        int orow = mb + wm + 16 * i + lg * 4 + r4;
        float v = acc[i][j][r4] * alpha;
        if (EPI == E_F32) {
          ((float*)Cg)[(size_t)orow * ldc + oc] = v;
        } else if (EPI == E_BF16) {
          ((unsigned short*)Cg)[(size_t)orow * ldc + oc] = f2bf(v);
        } else if (EPI == E_SWIGLU) {
          float other = __shfl_xor(v, 1);
          float g = (lane & 1) ? other : v;
          float vv = (lane & 1) ? v : other;
          float sw = g / (1.0f + expf(-g)) * vv;
          if (!(lane & 1))
            ((unsigned short*)Cg)[(size_t)orow * ldc + (oc >> 1)] = f2bf(sw);
        }
      }
    }
  }
}

// ============ 128x128 2-phase GEMM ==========================================
template <int EPI>
__global__ __launch_bounds__(256) void gemm_fast(
    const unsigned short* __restrict__ A, const unsigned short* __restrict__ B,
    void* __restrict__ Cg, int M, int N, int K, int lda, int ldb, int ldc,
    float alpha, int nbx)
{
  const int nwg = gridDim.x;
  const int orig = blockIdx.x;
  const int q = nwg >> 3, r = nwg & 7;
  const int xcd = orig & 7, rest = orig >> 3;
  const int wgid = (xcd < r ? xcd * (q + 1) : r * (q + 1) + (xcd - r) * q) + rest;
  const int bx = wgid % nbx, by = wgid / nbx;
  const int mb = by * 128;
  const int nb = bx * 128;

  const int Keff = (EPI == E_PART) ? (K >> 2) : K;   // split-K=4
  const int koff = (EPI == E_PART) ? blockIdx.z * Keff : 0;

  __shared__ __align__(16) unsigned short As[2][128 * 64];
  __shared__ __align__(16) unsigned short Bs[2][128 * 64];

  const int tid = threadIdx.x;
  const int lane = tid & 63;
  const int wave = tid >> 6;
  const int wm = (wave >> 1) * 64;
  const int wn = (wave & 1) * 64;
  const int lr = lane & 15;
  const int lg = lane >> 4;

  const int srow = lane >> 3;
  const int scol = ((lane & 7) ^ srow) * 8;

  f32x4 acc[4][4];
#pragma unroll
  for (int i = 0; i < 4; i++)
#pragma unroll
    for (int j = 0; j < 4; j++) acc[i][j] = (f32x4){0.f, 0.f, 0.f, 0.f};

  const unsigned short* Abase = A + (size_t)(mb + wave * 32 + srow) * lda + koff + scol;
  const unsigned short* Bbase = B + (size_t)(nb + wave * 32 + srow) * ldb + koff + scol;

  auto stage = [&](int kb, int b) {
#pragma unroll
    for (int c = 0; c < 4; c++)
      glds16(Abase + (size_t)(c * 8) * lda + kb, &As[b][(wave * 32 + c * 8) * 64]);
#pragma unroll
    for (int c = 0; c < 4; c++)
      glds16(Bbase + (size_t)(c * 8) * ldb + kb, &Bs[b][(wave * 32 + c * 8) * 64]);
  };

  stage(0, 0);
  __syncthreads();
  int cur = 0;
  const int nk = Keff >> 6;

  for (int t = 0; t < nk; ++t) {
    if (t + 1 < nk) stage((t + 1) << 6, cur ^ 1);

    short8 af[2][4], bfb[2][4];
#pragma unroll
    for (int h = 0; h < 2; h++) {
      const int swz = ((h * 4 + lg) ^ (lr & 7)) * 8;
#pragma unroll
      for (int i = 0; i < 4; i++) {
        af[h][i] = *(const short8*)&As[cur][(wm + 16 * i + lr) * 64 + swz];
        bfb[h][i] = *(const short8*)&Bs[cur][(wn + 16 * i + lr) * 64 + swz];
      }
    }
#pragma unroll
    for (int h = 0; h < 2; h++)
#pragma unroll
      for (int i = 0; i < 4; i++)
#pragma unroll
        for (int j = 0; j < 4; j++) MFMA(acc[i][j], af[h][i], bfb[h][j]);

    __syncthreads();
    cur ^= 1;
  }

#pragma unroll
  for (int i = 0; i < 4; i++) {
#pragma unroll
    for (int j = 0; j < 4; j++) {
      int oc = nb + wn + 16 * j + lr;
#pragma unroll
      for (int r4 = 0; r4 < 4; r4++) {
        int orow = mb + wm + 16 * i + lg * 4 + r4;
        float v = acc[i][j][r4] * alpha;
        if (EPI == E_F32) {
          ((float*)Cg)[(size_t)orow * ldc + oc] = v;
        } else if (EPI == E_BF16) {
          ((unsigned short*)Cg)[(size_t)orow * ldc + oc] = f2bf(v);
        } else {  // E_PART: partial slice z
          float* C = (float*)Cg + (size_t)blockIdx.z * ((size_t)L_SEQ * DMODEL);
          C[(size_t)orow * ldc + oc] = v;
        }
      }
    }
  }
}

// ---------------- fused flash attention (balanced, QBLK=64, 2 waves) --------
__global__ __launch_bounds__(128) void flash_attn(
    const unsigned short* __restrict__ Qg, const unsigned short* __restrict__ Kg,
    const unsigned short* __restrict__ Vt, unsigned short* __restrict__ Og,
    int ldq, int ldo)
{
  const int bid = blockIdx.x;
  const int slot = bid & 255, ph = bid >> 8;
  const int h = slot >> 4;
  const int qs = slot & 15;
  const int qb = ph ? (31 - qs) : qs;

  const int tid = threadIdx.x;
  const int lane = tid & 63;
  const int w = tid >> 6;
  const int lr = lane & 15;
  const int lg = lane >> 4;

  __shared__ __align__(16) unsigned short KsL[2][64 * 64];
  __shared__ __align__(16) unsigned short VsL[2][64 * 64];
  __shared__ __align__(16) unsigned short Ps[2][32 * 64];

  const int srow = lane >> 3;
  const int scol = ((lane & 7) ^ srow) * 8;

  short8 qf[2][2];
#pragma unroll
  for (int i = 0; i < 2; i++)
#pragma unroll
    for (int kk = 0; kk < 2; kk++)
      qf[i][kk] = *(const short8*)(Qg +
          (size_t)(qb * 64 + w * 32 + i * 16 + lr) * ldq + h * 64 + kk * 32 + lg * 8);

  f32x4 acc_o[2][4];
  float m_st[2][4], l_st[2][4];
#pragma unroll
  for (int i = 0; i < 2; i++)
#pragma unroll
    for (int j = 0; j < 4; j++) acc_o[i][j] = (f32x4){0.f, 0.f, 0.f, 0.f};
#pragma unroll
  for (int i = 0; i < 2; i++)
#pragma unroll
    for (int r = 0; r < 4; r++) { m_st[i][r] = -1e30f; l_st[i][r] = 0.f; }

  const int ntiles = qb + 1;
  const int qmin = qb * 64 + w * 32;

  auto stage = [&](int t, int buf) {
#pragma unroll
    for (int c = 0; c < 4; c++) {
      int row = w * 32 + c * 8 + srow;
      glds16(Kg + (size_t)(t * 64 + row) * ldq + h * 64 + scol,
             &KsL[buf][row * 64]);
      glds16(Vt + (size_t)(h * 64 + row) * L_SEQ + t * 64 + scol,
             &VsL[buf][row * 64]);
    }
  };

  stage(0, 0);
  __syncthreads();
  int buf = 0;

  for (int t = 0; t < ntiles; t++) {
    if (t + 1 < ntiles) stage(t + 1, buf ^ 1);

    f32x4 sa[2][4];
#pragma unroll
    for (int i = 0; i < 2; i++)
#pragma unroll
      for (int j = 0; j < 4; j++) sa[i][j] = (f32x4){0.f, 0.f, 0.f, 0.f};
#pragma unroll
    for (int kk = 0; kk < 2; kk++) {
      short8 kf[4];
#pragma unroll
      for (int j = 0; j < 4; j++)
        kf[j] = *(const short8*)&KsL[buf][(j * 16 + lr) * 64 + ((kk * 4 + lg) ^ (lr & 7)) * 8];
#pragma unroll
      for (int i = 0; i < 2; i++)
#pragma unroll
        for (int j = 0; j < 4; j++) MFMA(sa[i][j], qf[i][kk], kf[j]);
    }

    const bool diag = (t * 64 + 63) > qmin;
#pragma unroll
    for (int i = 0; i < 2; i++)
#pragma unroll
      for (int j = 0; j < 4; j++)
#pragma unroll
        for (int r = 0; r < 4; r++) {
          float s = sa[i][j][r] * 0.125f;
          if (diag) {
            int kg = t * 64 + j * 16 + lr;
            int qg = qmin + i * 16 + lg * 4 + r;
            if (kg > qg) s = -1e30f;
          }
          sa[i][j][r] = s;
        }

    float fsc[2][4], mnew[2][4];
#pragma unroll
    for (int i = 0; i < 2; i++)
#pragma unroll
      for (int r = 0; r < 4; r++) {
        float mx = fmaxf(fmaxf(sa[i][0][r], sa[i][1][r]), fmaxf(sa[i][2][r], sa[i][3][r]));
        mx = rmax16(mx);
        float mn = fmaxf(m_st[i][r], mx);
        mnew[i][r] = mn;
        fsc[i][r] = __expf(m_st[i][r] - mn);
        m_st[i][r] = mn;
      }
#pragma unroll
    for (int i = 0; i < 2; i++)
#pragma unroll
      for (int r = 0; r < 4; r++) {
        float ls = 0.f;
#pragma unroll
        for (int j = 0; j < 4; j++) {
          float p = __expf(sa[i][j][r] - mnew[i][r]);
          sa[i][j][r] = p;
          ls += p;
        }
        ls = rsum16(ls);
        l_st[i][r] = l_st[i][r] * fsc[i][r] + ls;
      }
#pragma unroll
    for (int i = 0; i < 2; i++)
#pragma unroll
      for (int j = 0; j < 4; j++)
#pragma unroll
        for (int r = 0; r < 4; r++) acc_o[i][j][r] *= fsc[i][r];

#pragma unroll
    for (int i = 0; i < 2; i++)
#pragma unroll
      for (int j = 0; j < 4; j++)
#pragma unroll
        for (int r = 0; r < 4; r++) {
          int qrl = lg * 4 + r;
          int idx = (i * 16 + qrl) * 64 + (((j * 2 + (lr >> 3)) ^ (qrl & 7)) * 8) + (lr & 7);
          Ps[w][idx] = f2bf(sa[i][j][r]);
        }

#pragma unroll
    for (int kk = 0; kk < 2; kk++) {
      short8 pf[2], vf[4];
#pragma unroll
      for (int i = 0; i < 2; i++)
        pf[i] = *(const short8*)&Ps[w][(i * 16 + lr) * 64 + ((kk * 4 + lg) ^ (lr & 7)) * 8];
#pragma unroll
      for (int j = 0; j < 4; j++)
        vf[j] = *(const short8*)&VsL[buf][(j * 16 + lr) * 64 + ((kk * 4 + lg) ^ (lr & 7)) * 8];
#pragma unroll
      for (int i = 0; i < 2; i++)
#pragma unroll
        for (int j = 0; j < 4; j++) MFMA(acc_o[i][j], pf[i], vf[j]);
    }

    __syncthreads();
    buf ^= 1;
  }

  float inv[2][4];
#pragma unroll
  for (int i = 0; i < 2; i++)
#pragma unroll
    for (int r = 0; r < 4; r++) inv[i][r] = 1.0f / l_st[i][r];
#pragma unroll
  for (int i = 0; i < 2; i++)
#pragma unroll
    for (int j = 0; j < 4; j++)
#pragma unroll
      for (int r = 0; r < 4; r++) {
        size_t row = qmin + i * 16 + lg * 4 + r;
        Og[row * ldo + h * 64 + j * 16 + lr] = f2bf(acc_o[i][j][r] * inv[i][r]);
      }
}

// rmsnorm with residual fold: xnew = x + sum of 4 partials (if fold)
__global__ __launch_bounds__(256) void rmsnorm_fold(
    const float* __restrict__ xin, const float* __restrict__ pb,
    unsigned short* __restrict__ o1, float* __restrict__ xout, int fold)
{
  int row = blockIdx.x;
  int tid = threadIdx.x;
  const size_t SL = (size_t)L_SEQ * DMODEL;
  float v[4];
  float ss = 0.f;
#pragma unroll
  for (int i = 0; i < 4; i++) {
    size_t idx = (size_t)row * DMODEL + tid + 256 * i;
    float val = xin[idx];
    if (fold) {
      val += pb[idx] + pb[idx + SL] + pb[idx + 2 * SL] + pb[idx + 3 * SL];
      xout[idx] = val;
    }
    v[i] = val;
    ss += val * val;
  }
#pragma unroll
  for (int o = 32; o > 0; o >>= 1) ss += __shfl_xor(ss, o);
  __shared__ float red[4];
  if ((tid & 63) == 0) red[tid >> 6] = ss;
  __syncthreads();
  ss = red[0] + red[1] + red[2] + red[3];
  float inv = rsqrtf(ss / DMODEL + 1e-6f);
#pragma unroll
  for (int i = 0; i < 4; i++) {
    size_t idx = (size_t)row * DMODEL + tid + 256 * i;
    o1[idx] = f2bf(v[i] * inv);
  }
}

// one launch: all weight prep for a layer; LN scales folded into weights
__global__ __launch_bounds__(256) void prep_weights(
    const float* __restrict__ wq, const float* __restrict__ wk,
    const float* __restrict__ wv, const float* __restrict__ wo,
    const float* __restrict__ gw, const float* __restrict__ vw,
    const float* __restrict__ fw, const float* __restrict__ s1,
    const float* __restrict__ s2,
    unsigned short* __restrict__ qkvw, unsigned short* __restrict__ wft,
    unsigned short* __restrict__ gvt)
{
  __shared__ float t0[32][33], t1[32][33];
  int bid = blockIdx.x;
  int tx = threadIdx.x, ty = threadIdx.y;
  if (bid < 4096) {
    int j = bid >> 10, tile = bid & 1023;
    int c0 = (tile & 31) * 32, r0 = (tile >> 5) * 32;
    const float* src = j == 0 ? wq : j == 1 ? wk : j == 2 ? wv : wo;
#pragma unroll
    for (int k = 0; k < 32; k += 8)
      t0[ty + k][tx] = src[(size_t)(r0 + ty + k) * 1024 + c0 + tx];
    __syncthreads();
    if (j < 3) {
      unsigned short* dst = qkvw + (size_t)j * 1024 * 1024;
      float sc = s1[r0 + tx];
#pragma unroll
      for (int k = 0; k < 32; k += 8)
        dst[(size_t)(c0 + ty + k) * 1024 + r0 + tx] = f2bf(t0[tx][ty + k] * sc);
    } else {
#pragma unroll
      for (int k = 0; k < 32; k += 8)
        wft[(size_t)(c0 + ty + k) * 5120 + r0 + tx] = f2bf(t0[tx][ty + k]);
    }
  } else if (bid < 8192) {
    int tile = bid - 4096;
    int c0 = (tile & 31) * 32;
    int r0 = (tile >> 5) * 32;
#pragma unroll
    for (int k = 0; k < 32; k += 8)
      t0[ty + k][tx] = fw[(size_t)(r0 + ty + k) * 1024 + c0 + tx];
    __syncthreads();
#pragma unroll
    for (int k = 0; k < 32; k += 8)
      wft[(size_t)(c0 + ty + k) * 5120 + 1024 + r0 + tx] = f2bf(t0[tx][ty + k]);
  } else {
    int tile = bid - 8192;
    int c0 = (tile & 127) * 32;
    int d0 = (tile >> 7) * 32;
#pragma unroll
    for (int k = 0; k < 32; k += 8) {
      t0[ty + k][tx] = gw[(size_t)(d0 + ty + k) * 4096 + c0 + tx];
      t1[ty + k][tx] = vw[(size_t)(d0 + ty + k) * 4096 + c0 + tx];
    }
    __syncthreads();
    float sc = s2[d0 + tx];
#pragma unroll
    for (int k = 0; k < 32; k += 8) {
      gvt[(size_t)(2 * (c0 + ty + k)) * 1024 + d0 + tx] = f2bf(t0[tx][ty + k] * sc);
      gvt[(size_t)(2 * (c0 + ty + k) + 1) * 1024 + d0 + tx] = f2bf(t1[tx][ty + k] * sc);
    }
  }
}

// activation transpose (V -> V^T) bf16 raw copy
__global__ __launch_bounds__(256) void transpose_act(
    const unsigned short* __restrict__ in, unsigned short* __restrict__ out,
    int ld_in, int ld_out)
{
  __shared__ unsigned short tile[32][33];
  int c0 = blockIdx.x * 32;
  int r0 = blockIdx.y * 32;
  int tx = threadIdx.x;
  int ty = threadIdx.y;
#pragma unroll
  for (int j = 0; j < 32; j += 8)
    tile[ty + j][tx] = in[(size_t)(r0 + ty + j) * ld_in + c0 + tx];
  __syncthreads();
#pragma unroll
  for (int j = 0; j < 32; j += 8)
    out[(size_t)(c0 + ty + j) * ld_out + r0 + tx] = tile[tx][ty + j];
}

// embb[v][d] = bf16(embed[v][d] * lnf[d])  (final-LN folded into tied embed)
__global__ __launch_bounds__(256) void convert_embb(
    const float* __restrict__ in, const float* __restrict__ lnf,
    unsigned short* __restrict__ out, size_t n)
{
  size_t i = ((size_t)blockIdx.x * 256 + threadIdx.x) * 4;
  if (i + 3 < n) {
    float4 v = *(const float4*)(in + i);
    int d = (int)(i & 1023);
    out[i] = f2bf(v.x * lnf[d]);
    out[i + 1] = f2bf(v.y * lnf[d + 1]);
    out[i + 2] = f2bf(v.z * lnf[d + 2]);
    out[i + 3] = f2bf(v.w * lnf[d + 3]);
  }
}

__global__ __launch_bounds__(256) void embed_kernel(
    const int* __restrict__ ids, const float* __restrict__ emb,
    const float* __restrict__ pos, float* __restrict__ x)
{
  int l = blockIdx.x;
  int id = ids[l];
#pragma unroll
  for (int i = 0; i < 4; i++) {
    int d = threadIdx.x + 256 * i;
    x[(size_t)l * DMODEL + d] = emb[(size_t)id * DMODEL + d] + pos[(size_t)l * DMODEL + d];
  }
}

extern "C" void kernel_launch(void* const* d_in, const int* in_sizes, int n_in,
                              void* d_out, int out_size, void* d_ws, size_t ws_size,
                              hipStream_t stream)
{
  const int L = L_SEQ, D = DMODEL, F = FFN_F, V = VOCAB;
  const int* ids = (const int*)d_in[0];
  const float* embed = (const float*)d_in[1];
  const float* pos = (const float*)d_in[2];
  const float* wq = (const float*)d_in[3];
  const float* wk = (const float*)d_in[4];
  const float* wv = (const float*)d_in[5];
  const float* wo = (const float*)d_in[6];
  const float* gatew = (const float*)d_in[7];
  const float* valw = (const float*)d_in[8];
  const float* ffow = (const float*)d_in[9];
  const float* ln1 = (const float*)d_in[10];
  const float* ln2 = (const float*)d_in[11];
  const float* lnf = (const float*)d_in[12];

  char* ws = (char*)d_ws;
  size_t off = 0;
  auto alloc = [&](size_t bytes) -> void* {
    void* p = ws + off;
    off += (bytes + 255) & ~(size_t)255;
    return p;
  };
  float* x = (float*)alloc((size_t)L * D * 4);
  float* pbuf = (float*)alloc((size_t)4 * L * D * 4);   // 4 split-K partials
  unsigned short* xhat = (unsigned short*)alloc((size_t)L * D * 2);
  unsigned short* qkvb = (unsigned short*)alloc((size_t)L * 3 * D * 2);
  unsigned short* vtb = (unsigned short*)alloc((size_t)L * D * 2);
  unsigned short* ohb = (unsigned short*)alloc((size_t)L * 5120 * 2);
  unsigned short* qkvw = (unsigned short*)alloc((size_t)3 * D * D * 2);
  unsigned short* gvt = (unsigned short*)alloc((size_t)2 * F * D * 2);
  unsigned short* wft = (unsigned short*)alloc((size_t)D * 5120 * 2);
  unsigned short* embb = (unsigned short*)alloc((size_t)V * D * 2);

  dim3 blk(256);
  dim3 blk512(512);
  dim3 blkT(32, 8);

  embed_kernel<<<L, blk, 0, stream>>>(ids, embed, pos, x);
  convert_embb<<<(unsigned)((size_t)V * D / 1024), blk, 0, stream>>>(
      embed, lnf, embb, (size_t)V * D);

  for (int i = 0; i < NLAYER; i++) {
    prep_weights<<<12288, blkT, 0, stream>>>(
        wq + (size_t)i * D * D, wk + (size_t)i * D * D, wv + (size_t)i * D * D,
        wo + (size_t)i * D * D, gatew + (size_t)i * D * F, valw + (size_t)i * D * F,
        ffow + (size_t)i * F * D, ln1 + (size_t)i * D, ln2 + (size_t)i * D,
        qkvw, wft, gvt);

    rmsnorm_fold<<<L, blk, 0, stream>>>(x, pbuf, xhat, x, i > 0 ? 1 : 0);

    // QKV projection (LN scale folded into qkvw); fully-resident 384 blocks
    gemm_fast<E_BF16><<<dim3(24 * 16), blk, 0, stream>>>(
        xhat, qkvw, qkvb, L, 3 * D, D, D, D, 3 * D, 1.0f, 24);

    transpose_act<<<dim3(D / 32, L / 32), blkT, 0, stream>>>(qkvb + 2 * D, vtb, 3 * D, L);

    flash_attn<<<dim3(512), dim3(128), 0, stream>>>(qkvb, qkvb + D, vtb, ohb, 3 * D, 5120);

    // swiglu (LN scale folded into gvt): exactly 256 blocks = 1 full wave
    gemm8p<E_SWIGLU><<<dim3(8 * 32), blk512, 0, stream>>>(
        xhat, gvt, ohb + 1024, L, 2 * F, D, D, D, 5120, 1.0f, 8);

    // combined output GEMM: [O | swiglu] * [wo^T ; ffo^T], split-K=4 partials
    gemm_fast<E_PART><<<dim3(8 * 16, 1, 4), blk, 0, stream>>>(
        ohb, wft, pbuf, L, D, 5120, 5120, 5120, D, 1.0f, 8);
  }

  rmsnorm_fold<<<L, blk, 0, stream>>>(x, pbuf, xhat, x, 1);
  gemm8p<E_F32><<<dim3(8 * 125), blk512, 0, stream>>>(
      xhat, embb, d_out, L, V, D, D, D, V, 1.0f, 8);
}